// Round 5
// baseline (103.923 us; speedup 1.0000x reference)
//
#include <hip/hip_runtime.h>
#include <math.h>

#define TNODES 8192
#define CC 128
#define RT 16
#define DEGCAP 128   // bucket capacity per src; degrees ~Poisson(39)+1, max~70

typedef __attribute__((ext_vector_type(8))) short bf8;
typedef __attribute__((ext_vector_type(4))) float fx4;

__device__ __forceinline__ ushort f2b(float f){
  union { float f; uint u; } a; a.f = f;
  uint u = a.u;
  uint r = (u + 0x7fffu + ((u >> 16) & 1u)) >> 16;   // RNE
  return (ushort)r;
}
__device__ __forceinline__ float b2f(ushort s){
  union { uint u; float f; } a; a.u = ((uint)s) << 16;
  return a.f;
}
__device__ __forceinline__ float2 bpair(uint u){
  union { uint u; float f; } lo, hi;
  lo.u = u << 16; hi.u = u & 0xffff0000u;
  float2 r; r.x = lo.f; r.y = hi.f; return r;
}
#define SWZ(row, col) ((col) ^ (((row) & 7) << 3))

// ---------------- S1: weight conv (208) + zero cnt (32) + full mod MLP (1) ----------------
__global__ __launch_bounds__(256) void s1_setup(
    const float* __restrict__ sw1, const float* __restrict__ wq, const float* __restrict__ wk,
    const float* __restrict__ wv, const float* __restrict__ wo, const float* __restrict__ fw1,
    const float* __restrict__ fw2, ushort* __restrict__ dst,
    int* __restrict__ cnt,
    const float* __restrict__ te, const float* __restrict__ mw1, const float* __restrict__ mb1,
    const float* __restrict__ mw2, const float* __restrict__ mb2, float* __restrict__ mod)
{
  const int b = blockIdx.x, tid = threadIdx.x;
  if (b < 208){
    int i = (b * 256 + tid) * 4;
    const float* src; int off;
    if      (i <  16384){ src = sw1; off = i; }
    else if (i <  32768){ src = wq;  off = i - 16384; }
    else if (i <  49152){ src = wk;  off = i - 32768; }
    else if (i <  65536){ src = wv;  off = i - 49152; }
    else if (i <  81920){ src = wo;  off = i - 65536; }
    else if (i < 147456){ src = fw1; off = i - 81920; }
    else                { src = fw2; off = i - 147456; }
    float4 v = *(const float4*)&src[off];
    ushort4 o; o.x = f2b(v.x); o.y = f2b(v.y); o.z = f2b(v.z); o.w = f2b(v.w);
    *(ushort4*)&dst[i] = o;
  } else if (b < 240){
    cnt[(b - 208) * 256 + tid] = 0;
  } else {
    // full mod MLP in one block: t = silu(te@mw1^T+mb1); mod = t@mw2^T+mb2
    __shared__ float teL[256];
    __shared__ float tL[256];
    teL[tid] = te[tid];
    __syncthreads();
    const int g = tid >> 4, th = tid & 15;   // 16 groups x 16 lanes
    #pragma unroll 4
    for (int it = 0; it < 16; ++it){
      int o = g*16 + it;
      float acc = 0.f;
      #pragma unroll
      for (int u = 0; u < 4; ++u){
        float4 w  = *(const float4*)&mw1[o*256 + th*16 + u*4];
        float4 t4 = *(const float4*)&teL[th*16 + u*4];
        acc += w.x*t4.x + w.y*t4.y + w.z*t4.z + w.w*t4.w;
      }
      #pragma unroll
      for (int m = 1; m < 16; m <<= 1) acc += __shfl_xor(acc, m);
      if (th == 0){
        float z = acc + mb1[o];
        tL[o] = z / (1.f + __expf(-z));
      }
    }
    __syncthreads();
    #pragma unroll 4
    for (int it = 0; it < 24; ++it){
      int o = g + 16*it;   // 0..383
      float acc = 0.f;
      #pragma unroll
      for (int u = 0; u < 4; ++u){
        float4 w  = *(const float4*)&mw2[o*256 + th*16 + u*4];
        float4 t4 = *(const float4*)&tL[th*16 + u*4];
        acc += w.x*t4.x + w.y*t4.y + w.z*t4.z + w.w*t4.w;
      }
      #pragma unroll
      for (int m = 1; m < 16; m <<= 1) acc += __shfl_xor(acc, m);
      if (th == 0) mod[o] = acc + mb2[o];
    }
  }
}

// ---------------- K2: siren -> y (LN+mod) -> QKV via MFMA  [+ scatter blocks] ----------------
__global__ __launch_bounds__(256) void k2_ctx_y_qkv(
    const float* __restrict__ x, const float* __restrict__ ce,
    const float* __restrict__ sw0, const float* __restrict__ sb0,
    const ushort* __restrict__ sw1b, const float* __restrict__ sb1,
    const ushort* __restrict__ wqb, const float* __restrict__ bq,
    const ushort* __restrict__ wkb, const float* __restrict__ bk,
    const ushort* __restrict__ wvb, const float* __restrict__ bv,
    const float* __restrict__ mod,
    ushort* __restrict__ Ybf, ushort* __restrict__ Qb, ushort* __restrict__ Kb, ushort* __restrict__ Vb,
    const int* __restrict__ ei, int E, int* __restrict__ cnt, int* __restrict__ adj)
{
  __shared__ float  ceL[RT][8];
  __shared__ ushort hxb[RT*CC];
  __shared__ float  yL[RT][132];
  __shared__ ushort yb[RT*CC];
  const int tid  = threadIdx.x;

  if (blockIdx.x >= TNODES/RT){
    // ---- bucket scatter (no count/scan passes) ----
    const int b = blockIdx.x - TNODES/RT;
    int e0 = (b * 256 + tid) * 4;
    if (e0 + 3 < E){
      int4 p0 = *(const int4*)&ei[2*e0];
      int4 p1 = *(const int4*)&ei[2*e0 + 4];
      int s;
      s = atomicAdd(&cnt[p0.x], 1); adj[p0.x*DEGCAP + (s & (DEGCAP-1))] = p0.y;
      s = atomicAdd(&cnt[p0.z], 1); adj[p0.z*DEGCAP + (s & (DEGCAP-1))] = p0.w;
      s = atomicAdd(&cnt[p1.x], 1); adj[p1.x*DEGCAP + (s & (DEGCAP-1))] = p1.y;
      s = atomicAdd(&cnt[p1.z], 1); adj[p1.z*DEGCAP + (s & (DEGCAP-1))] = p1.w;
    } else {
      for (int e = e0; e < E; ++e){
        int sr = ei[2*e], ds = ei[2*e+1];
        int s = atomicAdd(&cnt[sr], 1);
        adj[sr*DEGCAP + (s & (DEGCAP-1))] = ds;
      }
    }
    return;
  }

  const int lane = tid & 63, w = tid >> 6;
  const int l15 = lane & 15, lg = lane >> 4;
  const int row0 = blockIdx.x * RT;

  if (tid < RT*7){ int r = tid/7, i = tid - r*7; ceL[r][i] = ce[(row0+r)*7 + i]; }
  __syncthreads();

  // hctx = sin(ce @ sw0^T + sb0) -> bf16 LDS (swizzled)
  #pragma unroll
  for (int u = 0; u < 8; ++u){
    int idx = tid + u*256;
    int r = idx >> 7, j = idx & 127;
    float a = sb0[j];
    #pragma unroll
    for (int i = 0; i < 7; ++i) a += sw0[j*7+i]*ceL[r][i];
    hxb[r*CC + SWZ(r, j)] = f2b(__sinf(a));
  }
  __syncthreads();

  const int colb = w*32;
  // y_pre = x + hctx @ sw1^T + sb1 (prefetched fragments)
  {
    bf8 aH[4], bB[8];
    #pragma unroll
    for (int ks = 0; ks < 4; ++ks)
      aH[ks] = *(const bf8*)&hxb[l15*CC + SWZ(l15, ks*32 + lg*8)];
    #pragma unroll
    for (int ks = 0; ks < 4; ++ks)
      #pragma unroll
      for (int n = 0; n < 2; ++n)
        bB[ks*2+n] = *(const bf8*)&sw1b[(colb + n*16 + l15)*CC + ks*32 + lg*8];
    fx4 acc[2]; acc[0] = 0.f; acc[1] = 0.f;
    #pragma unroll
    for (int ks = 0; ks < 4; ++ks){
      acc[0] = __builtin_amdgcn_mfma_f32_16x16x32_bf16(aH[ks], bB[ks*2+0], acc[0], 0, 0, 0);
      acc[1] = __builtin_amdgcn_mfma_f32_16x16x32_bf16(aH[ks], bB[ks*2+1], acc[1], 0, 0, 0);
    }
    #pragma unroll
    for (int n = 0; n < 2; ++n)
      #pragma unroll
      for (int q = 0; q < 4; ++q){
        int r = lg*4 + q, c = colb + n*16 + l15;
        yL[r][c] = x[(row0+r)*CC + c] + acc[n][q] + sb1[c];
      }
  }
  __syncthreads();

  // LN over 128 + (1+a)*z + b -> bf16 LDS (swizzled)
  {
    int r = tid >> 4, s16 = tid & 15;
    float4 za = *(const float4*)&yL[r][s16*8];
    float4 zb = *(const float4*)&yL[r][s16*8 + 4];
    float sum = za.x+za.y+za.z+za.w + zb.x+zb.y+zb.z+zb.w;
    float ssq = za.x*za.x+za.y*za.y+za.z*za.z+za.w*za.w
              + zb.x*zb.x+zb.y*zb.y+zb.z*zb.z+zb.w*zb.w;
    #pragma unroll
    for (int m = 1; m < 16; m <<= 1){ sum += __shfl_xor(sum, m); ssq += __shfl_xor(ssq, m); }
    float mean = sum * (1.f/128.f);
    float var  = ssq * (1.f/128.f) - mean*mean;
    float inv  = rsqrtf(var + 1e-5f);
    float zv[8] = {za.x,za.y,za.z,za.w,zb.x,zb.y,zb.z,zb.w};
    bf8 pk;
    #pragma unroll
    for (int u = 0; u < 8; ++u){
      int jj = s16*8 + u;
      float z = (zv[u] - mean) * inv;
      pk[u] = (short)f2b((1.f + mod[jj]) * z + mod[128+jj]);
    }
    *(bf8*)&yb[r*CC + SWZ(r, s16*8)] = pk;
  }
  __syncthreads();

  // store Y (bf16)
  {
    int rr = tid >> 4, b8 = tid & 15;
    bf8 v = *(const bf8*)&yb[rr*CC + SWZ(rr, b8*8)];
    *(bf8*)&Ybf[(row0+rr)*CC + b8*8] = v;
  }

  // QKV: wave w = head w; q,k get per-head LN
  bf8 af[4];
  #pragma unroll
  for (int ks = 0; ks < 4; ++ks)
    af[ks] = *(const bf8*)&yb[l15*CC + SWZ(l15, ks*32 + lg*8)];

  const ushort* Wb[3] = {wqb, wkb, wvb};
  const float*  Bs[3] = {bq, bk, bv};
  ushort*       Ob[3] = {Qb, Kb, Vb};
  const int cb = w*32;
  #pragma unroll
  for (int m = 0; m < 3; ++m){
    bf8 bB[8];
    #pragma unroll
    for (int ks = 0; ks < 4; ++ks)
      #pragma unroll
      for (int n = 0; n < 2; ++n)
        bB[ks*2+n] = *(const bf8*)&Wb[m][(cb + n*16 + l15)*CC + ks*32 + lg*8];
    fx4 acc[2]; acc[0] = 0.f; acc[1] = 0.f;
    #pragma unroll
    for (int ks = 0; ks < 4; ++ks){
      acc[0] = __builtin_amdgcn_mfma_f32_16x16x32_bf16(af[ks], bB[ks*2+0], acc[0], 0, 0, 0);
      acc[1] = __builtin_amdgcn_mfma_f32_16x16x32_bf16(af[ks], bB[ks*2+1], acc[1], 0, 0, 0);
    }
    float vals[2][4];
    #pragma unroll
    for (int n = 0; n < 2; ++n)
      #pragma unroll
      for (int q = 0; q < 4; ++q)
        vals[n][q] = acc[n][q] + Bs[m][cb + n*16 + l15];
    if (m < 2){
      #pragma unroll
      for (int q = 0; q < 4; ++q){
        float s  = vals[0][q] + vals[1][q];
        float ss = vals[0][q]*vals[0][q] + vals[1][q]*vals[1][q];
        #pragma unroll
        for (int mm = 1; mm < 16; mm <<= 1){ s += __shfl_xor(s, mm); ss += __shfl_xor(ss, mm); }
        float mean = s * (1.f/32.f);
        float var  = ss * (1.f/32.f) - mean*mean;
        float inv  = rsqrtf(var + 1e-5f);
        vals[0][q] = (vals[0][q] - mean) * inv;
        vals[1][q] = (vals[1][q] - mean) * inv;
      }
    }
    #pragma unroll
    for (int n = 0; n < 2; ++n)
      #pragma unroll
      for (int q = 0; q < 4; ++q){
        int r = lg*4 + q, c = cb + n*16 + l15;
        Ob[m][(row0+r)*CC + c] = f2b(vals[n][q]);
      }
  }
}

// ---------------- K4: edge attention, 2 srcs per wave (one per 32-lane half) ----------------
__global__ __launch_bounds__(256) void k4_attn(
    const ushort* __restrict__ Qb, const ushort* __restrict__ Kb, const ushort* __restrict__ Vb,
    const int* __restrict__ cnt, const int* __restrict__ adj, ushort* __restrict__ Ab)
{
  const int wave = threadIdx.x >> 6, lane = threadIdx.x & 63;
  const int half = lane >> 5, hl = lane & 31;      // lane owns dims 4*hl..4*hl+3; head = hl>>3
  const int src = blockIdx.x*8 + wave*2 + half;

  uint2 qraw = *(const uint2*)&Qb[src*CC + 4*hl];
  float2 q0 = bpair(qraw.x), q1 = bpair(qraw.y);
  const float sc = 0.17677669529663687f;           // 1/sqrt(32)
  q0.x*=sc; q0.y*=sc; q1.x*=sc; q1.y*=sc;

  float a0=0.f, a1=0.f, a2=0.f, a3=0.f, dh=0.f;
  const int deg = min(cnt[src], DEGCAP);
  const int* ab = adj + src*DEGCAP;
  const int dmax = max(deg, __shfl_xor(deg, 32));

  for (int e = 0; e < dmax; e += 4){
    int4 dd = *(const int4*)&ab[e];
    // clamp OOB entries (beyond-deg slots hold poison) to a safe row
    int d0 = (e   < deg) ? dd.x : 0;
    int d1 = (e+1 < deg) ? dd.y : 0;
    int d2 = (e+2 < deg) ? dd.z : 0;
    int d3 = (e+3 < deg) ? dd.w : 0;
    uint2 k0 = *(const uint2*)&Kb[d0*CC + 4*hl];
    uint2 k1 = *(const uint2*)&Kb[d1*CC + 4*hl];
    uint2 k2 = *(const uint2*)&Kb[d2*CC + 4*hl];
    uint2 k3 = *(const uint2*)&Kb[d3*CC + 4*hl];
    uint2 v0 = *(const uint2*)&Vb[d0*CC + 4*hl];
    uint2 v1 = *(const uint2*)&Vb[d1*CC + 4*hl];
    uint2 v2 = *(const uint2*)&Vb[d2*CC + 4*hl];
    uint2 v3 = *(const uint2*)&Vb[d3*CC + 4*hl];
    float2 ka0 = bpair(k0.x), kb0 = bpair(k0.y);
    float2 ka1 = bpair(k1.x), kb1 = bpair(k1.y);
    float2 ka2 = bpair(k2.x), kb2 = bpair(k2.y);
    float2 ka3 = bpair(k3.x), kb3 = bpair(k3.y);
    float p0 = q0.x*ka0.x + q0.y*ka0.y + q1.x*kb0.x + q1.y*kb0.y;
    float p1 = q0.x*ka1.x + q0.y*ka1.y + q1.x*kb1.x + q1.y*kb1.y;
    float p2 = q0.x*ka2.x + q0.y*ka2.y + q1.x*kb2.x + q1.y*kb2.y;
    float p3 = q0.x*ka3.x + q0.y*ka3.y + q1.x*kb3.x + q1.y*kb3.y;
    // reduce over the 8 lanes of the head
    p0 += __shfl_xor(p0, 1); p1 += __shfl_xor(p1, 1); p2 += __shfl_xor(p2, 1); p3 += __shfl_xor(p3, 1);
    p0 += __shfl_xor(p0, 2); p1 += __shfl_xor(p1, 2); p2 += __shfl_xor(p2, 2); p3 += __shfl_xor(p3, 2);
    p0 += __shfl_xor(p0, 4); p1 += __shfl_xor(p1, 4); p2 += __shfl_xor(p2, 4); p3 += __shfl_xor(p3, 4);
    p0 = (e   < deg) ? __expf(p0) : 0.f;
    p1 = (e+1 < deg) ? __expf(p1) : 0.f;
    p2 = (e+2 < deg) ? __expf(p2) : 0.f;
    p3 = (e+3 < deg) ? __expf(p3) : 0.f;
    float2 va0 = bpair(v0.x), vb0 = bpair(v0.y);
    float2 va1 = bpair(v1.x), vb1 = bpair(v1.y);
    float2 va2 = bpair(v2.x), vb2 = bpair(v2.y);
    float2 va3 = bpair(v3.x), vb3 = bpair(v3.y);
    a0 += p0*va0.x + p1*va1.x + p2*va2.x + p3*va3.x;
    a1 += p0*va0.y + p1*va1.y + p2*va2.y + p3*va3.y;
    a2 += p0*vb0.x + p1*vb1.x + p2*vb2.x + p3*vb3.x;
    a3 += p0*vb0.y + p1*vb1.y + p2*vb2.y + p3*vb3.y;
    dh += p0 + p1 + p2 + p3;
  }
  float invd = 1.f / fmaxf(dh, 1e-9f);
  uint2 o;
  o.x = (uint)f2b(a0*invd) | ((uint)f2b(a1*invd) << 16);
  o.y = (uint)f2b(a2*invd) | ((uint)f2b(a3*invd) << 16);
  *(uint2*)&Ab[src*CC + 4*hl] = o;
}

// ---------------- K5: wo + residual + FFN + final mix (MFMA, prefetched) ----------------
__global__ __launch_bounds__(256) void k5_final(
    const float* __restrict__ x, const ushort* __restrict__ Ybf, const ushort* __restrict__ Ab,
    const ushort* __restrict__ wob, const float* __restrict__ bo,
    const ushort* __restrict__ fw1b, const float* __restrict__ fb1,
    const ushort* __restrict__ fw2b, const float* __restrict__ fb2,
    const float* __restrict__ mod, float* __restrict__ out)
{
  __shared__ ushort yyb[RT*CC];
  __shared__ ushort h1b[RT*512];
  const int tid  = threadIdx.x;
  const int lane = tid & 63, w = tid >> 6;
  const int l15 = lane & 15, lg = lane >> 4;
  const int row0 = blockIdx.x * RT;
  const int colb = w*32;

  // ---- wo GEMM (A from global, prefetched) ----
  {
    bf8 aA[4], bB[8];
    #pragma unroll
    for (int ks = 0; ks < 4; ++ks)
      aA[ks] = *(const bf8*)&Ab[(row0 + l15)*CC + ks*32 + lg*8];
    #pragma unroll
    for (int ks = 0; ks < 4; ++ks)
      #pragma unroll
      for (int n = 0; n < 2; ++n)
        bB[ks*2+n] = *(const bf8*)&wob[(colb + n*16 + l15)*CC + ks*32 + lg*8];
    fx4 acc[2]; acc[0] = 0.f; acc[1] = 0.f;
    #pragma unroll
    for (int ks = 0; ks < 4; ++ks){
      acc[0] = __builtin_amdgcn_mfma_f32_16x16x32_bf16(aA[ks], bB[ks*2+0], acc[0], 0, 0, 0);
      acc[1] = __builtin_amdgcn_mfma_f32_16x16x32_bf16(aA[ks], bB[ks*2+1], acc[1], 0, 0, 0);
    }
    #pragma unroll
    for (int n = 0; n < 2; ++n)
      #pragma unroll
      for (int q = 0; q < 4; ++q){
        int r = lg*4 + q, c = colb + n*16 + l15;
        float yy = b2f(Ybf[(row0+r)*CC + c]) + acc[n][q] + bo[c];
        yyb[r*CC + SWZ(r, c)] = f2b(yy);
      }
  }
  __syncthreads();

  // ---- fw1 + silu: wave w owns cols 128w..128w+127 ----
  {
    const int cb1 = w*128;
    bf8 aY[4];
    #pragma unroll
    for (int ks = 0; ks < 4; ++ks)
      aY[ks] = *(const bf8*)&yyb[l15*CC + SWZ(l15, ks*32 + lg*8)];
    fx4 h[8];
    #pragma unroll
    for (int n = 0; n < 8; ++n) h[n] = 0.f;
    #pragma unroll
    for (int g = 0; g < 2; ++g){
      #pragma unroll
      for (int kp = 0; kp < 2; ++kp){
        bf8 bB[8];
        #pragma unroll
        for (int kk = 0; kk < 2; ++kk)
          #pragma unroll
          for (int n = 0; n < 4; ++n)
            bB[kk*4+n] = *(const bf8*)&fw1b[(cb1 + (g*4+n)*16 + l15)*CC + (kp*2+kk)*32 + lg*8];
        #pragma unroll
        for (int kk = 0; kk < 2; ++kk)
          #pragma unroll
          for (int n = 0; n < 4; ++n)
            h[g*4+n] = __builtin_amdgcn_mfma_f32_16x16x32_bf16(aY[kp*2+kk], bB[kk*4+n], h[g*4+n], 0, 0, 0);
      }
    }
    #pragma unroll
    for (int n = 0; n < 8; ++n)
      #pragma unroll
      for (int q = 0; q < 4; ++q){
        int r = lg*4 + q, c = cb1 + n*16 + l15;
        float z = h[n][q] + fb1[c];
        float sl = z / (1.f + __expf(-z));
        h1b[r*512 + SWZ(r, c)] = f2b(sl);
      }
  }
  __syncthreads();

  // ---- fw2: wave w owns cols 32w..32w+31, K=512 ----
  {
    fx4 acc[2]; acc[0] = 0.f; acc[1] = 0.f;
    #pragma unroll
    for (int g4 = 0; g4 < 4; ++g4){
      bf8 aH[4], bB[8];
      #pragma unroll
      for (int kk = 0; kk < 4; ++kk)
        aH[kk] = *(const bf8*)&h1b[l15*512 + SWZ(l15, (g4*4+kk)*32 + lg*8)];
      #pragma unroll
      for (int kk = 0; kk < 4; ++kk)
        #pragma unroll
        for (int n = 0; n < 2; ++n)
          bB[kk*2+n] = *(const bf8*)&fw2b[(colb + n*16 + l15)*512 + (g4*4+kk)*32 + lg*8];
      #pragma unroll
      for (int kk = 0; kk < 4; ++kk){
        acc[0] = __builtin_amdgcn_mfma_f32_16x16x32_bf16(aH[kk], bB[kk*2+0], acc[0], 0, 0, 0);
        acc[1] = __builtin_amdgcn_mfma_f32_16x16x32_bf16(aH[kk], bB[kk*2+1], acc[1], 0, 0, 0);
      }
    }
    #pragma unroll
    for (int n = 0; n < 2; ++n)
      #pragma unroll
      for (int q = 0; q < 4; ++q){
        int r = lg*4 + q, c = colb + n*16 + l15;
        int g = row0 + r;
        float cj = mod[256 + c];
        float y2 = acc[n][q] + fb2[c];
        out[g*CC + c] = (x[g*CC + c] + cj*y2) * rsqrtf(1.f + cj*cj);
      }
  }
}

extern "C" void kernel_launch(void* const* d_in, const int* in_sizes, int n_in,
                              void* d_out, int out_size, void* d_ws, size_t ws_size,
                              hipStream_t stream)
{
  const float* x   = (const float*)d_in[0];
  const float* te  = (const float*)d_in[1];
  const float* ce  = (const float*)d_in[2];
  const int*   ei  = (const int*)  d_in[3];
  const float* mw1 = (const float*)d_in[4];
  const float* mb1 = (const float*)d_in[5];
  const float* mw2 = (const float*)d_in[6];
  const float* mb2 = (const float*)d_in[7];
  const float* sw0 = (const float*)d_in[8];
  const float* sb0 = (const float*)d_in[9];
  const float* sw1 = (const float*)d_in[10];
  const float* sb1 = (const float*)d_in[11];
  const float* wq  = (const float*)d_in[12];
  const float* bq  = (const float*)d_in[13];
  const float* wk  = (const float*)d_in[14];
  const float* bk  = (const float*)d_in[15];
  const float* wv  = (const float*)d_in[16];
  const float* bv  = (const float*)d_in[17];
  const float* wo  = (const float*)d_in[18];
  const float* bo  = (const float*)d_in[19];
  const float* fw1 = (const float*)d_in[20];
  const float* fb1 = (const float*)d_in[21];
  const float* fw2 = (const float*)d_in[22];
  const float* fb2 = (const float*)d_in[23];
  float* out = (float*)d_out;
  const int E = in_sizes[3] / 2;

  float* ws   = (float*)d_ws;
  float* mod  = ws;                           // 384 (pad 1024)
  ushort* WB  = (ushort*)(ws + 1024);         // 212992 bf16 weights
  ushort* sw1b = WB;
  ushort* wqb  = WB + 16384;
  ushort* wkb  = WB + 32768;
  ushort* wvb  = WB + 49152;
  ushort* wob  = WB + 65536;
  ushort* fw1b = WB + 81920;
  ushort* fw2b = WB + 147456;
  ushort* Ybf = WB + 212992;
  ushort* Qb  = Ybf + TNODES*CC;
  ushort* Kb  = Qb  + TNODES*CC;
  ushort* Vb  = Kb  + TNODES*CC;
  ushort* Ab  = Vb  + TNODES*CC;
  int* cnt    = (int*)(Ab + TNODES*CC);       // TN counts
  int* adj    = cnt + TNODES;                 // TN*DEGCAP bucket adjacency

  const int nSB = (E + 1023) / 1024;

  s1_setup<<<241, 256, 0, stream>>>(sw1, wq, wk, wv, wo, fw1, fw2, WB, cnt,
                                    te, mw1, mb1, mw2, mb2, mod);
  k2_ctx_y_qkv<<<TNODES/RT + nSB, 256, 0, stream>>>(x, ce, sw0, sb0, sw1b, sb1,
                                              wqb, bq, wkb, bk, wvb, bv, mod, Ybf, Qb, Kb, Vb,
                                              ei, E, cnt, adj);
  k4_attn<<<TNODES/8, 256, 0, stream>>>(Qb, Kb, Vb, cnt, adj, Ab);
  k5_final<<<TNODES/RT, 256, 0, stream>>>(x, Ybf, Ab, wob, bo, fw1b, fb1, fw2b, fb2, mod, out);
}

// Round 6
// 83.319 us; speedup vs baseline: 1.2473x; 1.2473x over previous
//
#include <hip/hip_runtime.h>
#include <math.h>

#define TNODES 8192
#define CC 128
#define RT 16
#define DEGCAP 128   // bucket capacity per src; degrees ~Poisson(39)+1, max~70

typedef __attribute__((ext_vector_type(8))) short bf8;
typedef __attribute__((ext_vector_type(4))) float fx4;

__device__ __forceinline__ ushort f2b(float f){
  union { float f; uint u; } a; a.f = f;
  uint u = a.u;
  uint r = (u + 0x7fffu + ((u >> 16) & 1u)) >> 16;   // RNE
  return (ushort)r;
}
__device__ __forceinline__ float b2f(ushort s){
  union { uint u; float f; } a; a.u = ((uint)s) << 16;
  return a.f;
}
__device__ __forceinline__ float2 bpair(uint u){
  union { uint u; float f; } lo, hi;
  lo.u = u << 16; hi.u = u & 0xffff0000u;
  float2 r; r.x = lo.f; r.y = hi.f; return r;
}
#define SWZ(row, col) ((col) ^ (((row) & 7) << 3))

// ---------------- S1: weight conv (208) + zero cnt (32) + mod layer1 (16 blocks) ----------------
__global__ __launch_bounds__(256) void s1_setup(
    const float* __restrict__ sw1, const float* __restrict__ wq, const float* __restrict__ wk,
    const float* __restrict__ wv, const float* __restrict__ wo, const float* __restrict__ fw1,
    const float* __restrict__ fw2, ushort* __restrict__ dst,
    int* __restrict__ cnt,
    const float* __restrict__ te, const float* __restrict__ mw1, const float* __restrict__ mb1,
    float* __restrict__ tbuf)
{
  const int b = blockIdx.x, tid = threadIdx.x;
  if (b < 208){
    int i = (b * 256 + tid) * 4;
    const float* src; int off;
    if      (i <  16384){ src = sw1; off = i; }
    else if (i <  32768){ src = wq;  off = i - 16384; }
    else if (i <  49152){ src = wk;  off = i - 32768; }
    else if (i <  65536){ src = wv;  off = i - 49152; }
    else if (i <  81920){ src = wo;  off = i - 65536; }
    else if (i < 147456){ src = fw1; off = i - 81920; }
    else                { src = fw2; off = i - 147456; }
    float4 v = *(const float4*)&src[off];
    ushort4 o; o.x = f2b(v.x); o.y = f2b(v.y); o.z = f2b(v.z); o.w = f2b(v.w);
    *(ushort4*)&dst[i] = o;
  } else if (b < 240){
    cnt[(b - 208) * 256 + tid] = 0;
  } else {
    // mod layer1: t = silu(te @ mw1^T + mb1), 16 outputs/block, 16 threads/output
    const int og = tid >> 4, th = tid & 15;
    const int o = (b - 240) * 16 + og;
    float acc = 0.f;
    #pragma unroll
    for (int u = 0; u < 4; ++u){
      float4 w  = *(const float4*)&mw1[o*256 + th*16 + u*4];
      float4 t4 = *(const float4*)&te[th*16 + u*4];
      acc += w.x*t4.x + w.y*t4.y + w.z*t4.z + w.w*t4.w;
    }
    #pragma unroll
    for (int m = 1; m < 16; m <<= 1) acc += __shfl_xor(acc, m);
    if (th == 0){
      float z = acc + mb1[o];
      tbuf[o] = z / (1.f + __expf(-z));
    }
  }
}

// ---------------- S2: bucket scatter (no count/scan) + mod layer2 ----------------
__global__ __launch_bounds__(256) void s2_setup(
    const int* __restrict__ ei, int E, int nSB, int* __restrict__ cnt, int* __restrict__ adj,
    const float* __restrict__ tbuf, const float* __restrict__ mw2, const float* __restrict__ mb2,
    float* __restrict__ mod)
{
  const int b = blockIdx.x, tid = threadIdx.x;
  if (b < nSB){
    int e0 = (b * 256 + tid) * 4;
    if (e0 + 3 < E){
      int4 p0 = *(const int4*)&ei[2*e0];
      int4 p1 = *(const int4*)&ei[2*e0 + 4];
      int s;
      s = atomicAdd(&cnt[p0.x], 1); adj[p0.x*DEGCAP + (s & (DEGCAP-1))] = p0.y;
      s = atomicAdd(&cnt[p0.z], 1); adj[p0.z*DEGCAP + (s & (DEGCAP-1))] = p0.w;
      s = atomicAdd(&cnt[p1.x], 1); adj[p1.x*DEGCAP + (s & (DEGCAP-1))] = p1.y;
      s = atomicAdd(&cnt[p1.z], 1); adj[p1.z*DEGCAP + (s & (DEGCAP-1))] = p1.w;
    } else {
      for (int e = e0; e < E; ++e){
        int sr = ei[2*e], ds = ei[2*e+1];
        int s = atomicAdd(&cnt[sr], 1);
        adj[sr*DEGCAP + (s & (DEGCAP-1))] = ds;
      }
    }
  } else {
    const int og = tid >> 4, th = tid & 15;
    const int o = (b - nSB) * 16 + og;   // < 384
    float acc = 0.f;
    #pragma unroll
    for (int u = 0; u < 4; ++u){
      float4 w  = *(const float4*)&mw2[o*256 + th*16 + u*4];
      float4 t4 = *(const float4*)&tbuf[th*16 + u*4];
      acc += w.x*t4.x + w.y*t4.y + w.z*t4.z + w.w*t4.w;
    }
    #pragma unroll
    for (int m = 1; m < 16; m <<= 1) acc += __shfl_xor(acc, m);
    if (th == 0) mod[o] = acc + mb2[o];
  }
}

// ---------------- K2: siren -> y (LN+mod) -> QKV via MFMA ----------------
__global__ __launch_bounds__(256) void k2_ctx_y_qkv(
    const float* __restrict__ x, const float* __restrict__ ce,
    const float* __restrict__ sw0, const float* __restrict__ sb0,
    const ushort* __restrict__ sw1b, const float* __restrict__ sb1,
    const ushort* __restrict__ wqb, const float* __restrict__ bq,
    const ushort* __restrict__ wkb, const float* __restrict__ bk,
    const ushort* __restrict__ wvb, const float* __restrict__ bv,
    const float* __restrict__ mod,
    ushort* __restrict__ Ybf, ushort* __restrict__ Qb, ushort* __restrict__ Kb, ushort* __restrict__ Vb)
{
  __shared__ float  ceL[RT][8];
  __shared__ ushort hxb[RT*CC];
  __shared__ float  yL[RT][132];
  __shared__ ushort yb[RT*CC];
  const int tid  = threadIdx.x;
  const int lane = tid & 63, w = tid >> 6;
  const int l15 = lane & 15, lg = lane >> 4;
  const int row0 = blockIdx.x * RT;

  if (tid < RT*7){ int r = tid/7, i = tid - r*7; ceL[r][i] = ce[(row0+r)*7 + i]; }
  __syncthreads();

  // hctx = sin(ce @ sw0^T + sb0) -> bf16 LDS (swizzled)
  #pragma unroll
  for (int u = 0; u < 8; ++u){
    int idx = tid + u*256;
    int r = idx >> 7, j = idx & 127;
    float a = sb0[j];
    #pragma unroll
    for (int i = 0; i < 7; ++i) a += sw0[j*7+i]*ceL[r][i];
    hxb[r*CC + SWZ(r, j)] = f2b(__sinf(a));
  }
  __syncthreads();

  const int colb = w*32;
  // y_pre = x + hctx @ sw1^T + sb1 (prefetched fragments)
  {
    bf8 aH[4], bB[8];
    #pragma unroll
    for (int ks = 0; ks < 4; ++ks)
      aH[ks] = *(const bf8*)&hxb[l15*CC + SWZ(l15, ks*32 + lg*8)];
    #pragma unroll
    for (int ks = 0; ks < 4; ++ks)
      #pragma unroll
      for (int n = 0; n < 2; ++n)
        bB[ks*2+n] = *(const bf8*)&sw1b[(colb + n*16 + l15)*CC + ks*32 + lg*8];
    fx4 acc[2]; acc[0] = 0.f; acc[1] = 0.f;
    #pragma unroll
    for (int ks = 0; ks < 4; ++ks){
      acc[0] = __builtin_amdgcn_mfma_f32_16x16x32_bf16(aH[ks], bB[ks*2+0], acc[0], 0, 0, 0);
      acc[1] = __builtin_amdgcn_mfma_f32_16x16x32_bf16(aH[ks], bB[ks*2+1], acc[1], 0, 0, 0);
    }
    #pragma unroll
    for (int n = 0; n < 2; ++n)
      #pragma unroll
      for (int q = 0; q < 4; ++q){
        int r = lg*4 + q, c = colb + n*16 + l15;
        yL[r][c] = x[(row0+r)*CC + c] + acc[n][q] + sb1[c];
      }
  }
  __syncthreads();

  // LN over 128 + (1+a)*z + b -> bf16 LDS (swizzled)
  {
    int r = tid >> 4, s16 = tid & 15;
    float4 za = *(const float4*)&yL[r][s16*8];
    float4 zb = *(const float4*)&yL[r][s16*8 + 4];
    float sum = za.x+za.y+za.z+za.w + zb.x+zb.y+zb.z+zb.w;
    float ssq = za.x*za.x+za.y*za.y+za.z*za.z+za.w*za.w
              + zb.x*zb.x+zb.y*zb.y+zb.z*zb.z+zb.w*zb.w;
    #pragma unroll
    for (int m = 1; m < 16; m <<= 1){ sum += __shfl_xor(sum, m); ssq += __shfl_xor(ssq, m); }
    float mean = sum * (1.f/128.f);
    float var  = ssq * (1.f/128.f) - mean*mean;
    float inv  = rsqrtf(var + 1e-5f);
    float zv[8] = {za.x,za.y,za.z,za.w,zb.x,zb.y,zb.z,zb.w};
    bf8 pk;
    #pragma unroll
    for (int u = 0; u < 8; ++u){
      int jj = s16*8 + u;
      float z = (zv[u] - mean) * inv;
      pk[u] = (short)f2b((1.f + mod[jj]) * z + mod[128+jj]);
    }
    *(bf8*)&yb[r*CC + SWZ(r, s16*8)] = pk;
  }
  __syncthreads();

  // store Y (bf16)
  {
    int rr = tid >> 4, b8 = tid & 15;
    bf8 v = *(const bf8*)&yb[rr*CC + SWZ(rr, b8*8)];
    *(bf8*)&Ybf[(row0+rr)*CC + b8*8] = v;
  }

  // QKV: wave w = head w; q,k get per-head LN
  bf8 af[4];
  #pragma unroll
  for (int ks = 0; ks < 4; ++ks)
    af[ks] = *(const bf8*)&yb[l15*CC + SWZ(l15, ks*32 + lg*8)];

  const ushort* Wb[3] = {wqb, wkb, wvb};
  const float*  Bs[3] = {bq, bk, bv};
  ushort*       Ob[3] = {Qb, Kb, Vb};
  const int cb = w*32;
  #pragma unroll
  for (int m = 0; m < 3; ++m){
    bf8 bB[8];
    #pragma unroll
    for (int ks = 0; ks < 4; ++ks)
      #pragma unroll
      for (int n = 0; n < 2; ++n)
        bB[ks*2+n] = *(const bf8*)&Wb[m][(cb + n*16 + l15)*CC + ks*32 + lg*8];
    fx4 acc[2]; acc[0] = 0.f; acc[1] = 0.f;
    #pragma unroll
    for (int ks = 0; ks < 4; ++ks){
      acc[0] = __builtin_amdgcn_mfma_f32_16x16x32_bf16(af[ks], bB[ks*2+0], acc[0], 0, 0, 0);
      acc[1] = __builtin_amdgcn_mfma_f32_16x16x32_bf16(af[ks], bB[ks*2+1], acc[1], 0, 0, 0);
    }
    float vals[2][4];
    #pragma unroll
    for (int n = 0; n < 2; ++n)
      #pragma unroll
      for (int q = 0; q < 4; ++q)
        vals[n][q] = acc[n][q] + Bs[m][cb + n*16 + l15];
    if (m < 2){
      #pragma unroll
      for (int q = 0; q < 4; ++q){
        float s  = vals[0][q] + vals[1][q];
        float ss = vals[0][q]*vals[0][q] + vals[1][q]*vals[1][q];
        #pragma unroll
        for (int mm = 1; mm < 16; mm <<= 1){ s += __shfl_xor(s, mm); ss += __shfl_xor(ss, mm); }
        float mean = s * (1.f/32.f);
        float var  = ss * (1.f/32.f) - mean*mean;
        float inv  = rsqrtf(var + 1e-5f);
        vals[0][q] = (vals[0][q] - mean) * inv;
        vals[1][q] = (vals[1][q] - mean) * inv;
      }
    }
    #pragma unroll
    for (int n = 0; n < 2; ++n)
      #pragma unroll
      for (int q = 0; q < 4; ++q){
        int r = lg*4 + q, c = cb + n*16 + l15;
        Ob[m][(row0+r)*CC + c] = f2b(vals[n][q]);
      }
  }
}

// ---------------- K4: edge attention, 2 srcs per wave (one per 32-lane half) ----------------
__global__ __launch_bounds__(256) void k4_attn(
    const ushort* __restrict__ Qb, const ushort* __restrict__ Kb, const ushort* __restrict__ Vb,
    const int* __restrict__ cnt, const int* __restrict__ adj, ushort* __restrict__ Ab)
{
  const int wave = threadIdx.x >> 6, lane = threadIdx.x & 63;
  const int half = lane >> 5, hl = lane & 31;      // lane owns dims 4*hl..4*hl+3; head = hl>>3
  const int src = blockIdx.x*8 + wave*2 + half;

  uint2 qraw = *(const uint2*)&Qb[src*CC + 4*hl];
  float2 q0 = bpair(qraw.x), q1 = bpair(qraw.y);
  const float sc = 0.17677669529663687f;           // 1/sqrt(32)
  q0.x*=sc; q0.y*=sc; q1.x*=sc; q1.y*=sc;

  float a0=0.f, a1=0.f, a2=0.f, a3=0.f, dh=0.f;
  const int deg = min(cnt[src], DEGCAP);
  const int* ab = adj + src*DEGCAP;
  const int dmax = max(deg, __shfl_xor(deg, 32));

  for (int e = 0; e < dmax; e += 4){
    int4 dd = *(const int4*)&ab[e];
    // clamp OOB entries (beyond-deg slots hold poison) to a safe row
    int d0 = (e   < deg) ? dd.x : 0;
    int d1 = (e+1 < deg) ? dd.y : 0;
    int d2 = (e+2 < deg) ? dd.z : 0;
    int d3 = (e+3 < deg) ? dd.w : 0;
    uint2 k0 = *(const uint2*)&Kb[d0*CC + 4*hl];
    uint2 k1 = *(const uint2*)&Kb[d1*CC + 4*hl];
    uint2 k2 = *(const uint2*)&Kb[d2*CC + 4*hl];
    uint2 k3 = *(const uint2*)&Kb[d3*CC + 4*hl];
    uint2 v0 = *(const uint2*)&Vb[d0*CC + 4*hl];
    uint2 v1 = *(const uint2*)&Vb[d1*CC + 4*hl];
    uint2 v2 = *(const uint2*)&Vb[d2*CC + 4*hl];
    uint2 v3 = *(const uint2*)&Vb[d3*CC + 4*hl];
    float2 ka0 = bpair(k0.x), kb0 = bpair(k0.y);
    float2 ka1 = bpair(k1.x), kb1 = bpair(k1.y);
    float2 ka2 = bpair(k2.x), kb2 = bpair(k2.y);
    float2 ka3 = bpair(k3.x), kb3 = bpair(k3.y);
    float p0 = q0.x*ka0.x + q0.y*ka0.y + q1.x*kb0.x + q1.y*kb0.y;
    float p1 = q0.x*ka1.x + q0.y*ka1.y + q1.x*kb1.x + q1.y*kb1.y;
    float p2 = q0.x*ka2.x + q0.y*ka2.y + q1.x*kb2.x + q1.y*kb2.y;
    float p3 = q0.x*ka3.x + q0.y*ka3.y + q1.x*kb3.x + q1.y*kb3.y;
    // reduce over the 8 lanes of the head
    p0 += __shfl_xor(p0, 1); p1 += __shfl_xor(p1, 1); p2 += __shfl_xor(p2, 1); p3 += __shfl_xor(p3, 1);
    p0 += __shfl_xor(p0, 2); p1 += __shfl_xor(p1, 2); p2 += __shfl_xor(p2, 2); p3 += __shfl_xor(p3, 2);
    p0 += __shfl_xor(p0, 4); p1 += __shfl_xor(p1, 4); p2 += __shfl_xor(p2, 4); p3 += __shfl_xor(p3, 4);
    p0 = (e   < deg) ? __expf(p0) : 0.f;
    p1 = (e+1 < deg) ? __expf(p1) : 0.f;
    p2 = (e+2 < deg) ? __expf(p2) : 0.f;
    p3 = (e+3 < deg) ? __expf(p3) : 0.f;
    float2 va0 = bpair(v0.x), vb0 = bpair(v0.y);
    float2 va1 = bpair(v1.x), vb1 = bpair(v1.y);
    float2 va2 = bpair(v2.x), vb2 = bpair(v2.y);
    float2 va3 = bpair(v3.x), vb3 = bpair(v3.y);
    a0 += p0*va0.x + p1*va1.x + p2*va2.x + p3*va3.x;
    a1 += p0*va0.y + p1*va1.y + p2*va2.y + p3*va3.y;
    a2 += p0*vb0.x + p1*vb1.x + p2*vb2.x + p3*vb3.x;
    a3 += p0*vb0.y + p1*vb1.y + p2*vb2.y + p3*vb3.y;
    dh += p0 + p1 + p2 + p3;
  }
  float invd = 1.f / fmaxf(dh, 1e-9f);
  uint2 o;
  o.x = (uint)f2b(a0*invd) | ((uint)f2b(a1*invd) << 16);
  o.y = (uint)f2b(a2*invd) | ((uint)f2b(a3*invd) << 16);
  *(uint2*)&Ab[src*CC + 4*hl] = o;
}

// ---------------- K5: wo + residual + FFN + final mix (MFMA, prefetched) ----------------
__global__ __launch_bounds__(256) void k5_final(
    const float* __restrict__ x, const ushort* __restrict__ Ybf, const ushort* __restrict__ Ab,
    const ushort* __restrict__ wob, const float* __restrict__ bo,
    const ushort* __restrict__ fw1b, const float* __restrict__ fb1,
    const ushort* __restrict__ fw2b, const float* __restrict__ fb2,
    const float* __restrict__ mod, float* __restrict__ out)
{
  __shared__ ushort yyb[RT*CC];
  __shared__ ushort h1b[RT*512];
  const int tid  = threadIdx.x;
  const int lane = tid & 63, w = tid >> 6;
  const int l15 = lane & 15, lg = lane >> 4;
  const int row0 = blockIdx.x * RT;
  const int colb = w*32;

  // ---- wo GEMM (A from global, prefetched) ----
  {
    bf8 aA[4], bB[8];
    #pragma unroll
    for (int ks = 0; ks < 4; ++ks)
      aA[ks] = *(const bf8*)&Ab[(row0 + l15)*CC + ks*32 + lg*8];
    #pragma unroll
    for (int ks = 0; ks < 4; ++ks)
      #pragma unroll
      for (int n = 0; n < 2; ++n)
        bB[ks*2+n] = *(const bf8*)&wob[(colb + n*16 + l15)*CC + ks*32 + lg*8];
    fx4 acc[2]; acc[0] = 0.f; acc[1] = 0.f;
    #pragma unroll
    for (int ks = 0; ks < 4; ++ks){
      acc[0] = __builtin_amdgcn_mfma_f32_16x16x32_bf16(aA[ks], bB[ks*2+0], acc[0], 0, 0, 0);
      acc[1] = __builtin_amdgcn_mfma_f32_16x16x32_bf16(aA[ks], bB[ks*2+1], acc[1], 0, 0, 0);
    }
    #pragma unroll
    for (int n = 0; n < 2; ++n)
      #pragma unroll
      for (int q = 0; q < 4; ++q){
        int r = lg*4 + q, c = colb + n*16 + l15;
        float yy = b2f(Ybf[(row0+r)*CC + c]) + acc[n][q] + bo[c];
        yyb[r*CC + SWZ(r, c)] = f2b(yy);
      }
  }
  __syncthreads();

  // ---- fw1 + silu: wave w owns cols 128w..128w+127 ----
  {
    const int cb1 = w*128;
    bf8 aY[4];
    #pragma unroll
    for (int ks = 0; ks < 4; ++ks)
      aY[ks] = *(const bf8*)&yyb[l15*CC + SWZ(l15, ks*32 + lg*8)];
    fx4 h[8];
    #pragma unroll
    for (int n = 0; n < 8; ++n) h[n] = 0.f;
    #pragma unroll
    for (int g = 0; g < 2; ++g){
      #pragma unroll
      for (int kp = 0; kp < 2; ++kp){
        bf8 bB[8];
        #pragma unroll
        for (int kk = 0; kk < 2; ++kk)
          #pragma unroll
          for (int n = 0; n < 4; ++n)
            bB[kk*4+n] = *(const bf8*)&fw1b[(cb1 + (g*4+n)*16 + l15)*CC + (kp*2+kk)*32 + lg*8];
        #pragma unroll
        for (int kk = 0; kk < 2; ++kk)
          #pragma unroll
          for (int n = 0; n < 4; ++n)
            h[g*4+n] = __builtin_amdgcn_mfma_f32_16x16x32_bf16(aY[kp*2+kk], bB[kk*4+n], h[g*4+n], 0, 0, 0);
      }
    }
    #pragma unroll
    for (int n = 0; n < 8; ++n)
      #pragma unroll
      for (int q = 0; q < 4; ++q){
        int r = lg*4 + q, c = cb1 + n*16 + l15;
        float z = h[n][q] + fb1[c];
        float sl = z / (1.f + __expf(-z));
        h1b[r*512 + SWZ(r, c)] = f2b(sl);
      }
  }
  __syncthreads();

  // ---- fw2: wave w owns cols 32w..32w+31, K=512 ----
  {
    fx4 acc[2]; acc[0] = 0.f; acc[1] = 0.f;
    #pragma unroll
    for (int g4 = 0; g4 < 4; ++g4){
      bf8 aH[4], bB[8];
      #pragma unroll
      for (int kk = 0; kk < 4; ++kk)
        aH[kk] = *(const bf8*)&h1b[l15*512 + SWZ(l15, (g4*4+kk)*32 + lg*8)];
      #pragma unroll
      for (int kk = 0; kk < 4; ++kk)
        #pragma unroll
        for (int n = 0; n < 2; ++n)
          bB[kk*2+n] = *(const bf8*)&fw2b[(colb + n*16 + l15)*512 + (g4*4+kk)*32 + lg*8];
      #pragma unroll
      for (int kk = 0; kk < 4; ++kk){
        acc[0] = __builtin_amdgcn_mfma_f32_16x16x32_bf16(aH[kk], bB[kk*2+0], acc[0], 0, 0, 0);
        acc[1] = __builtin_amdgcn_mfma_f32_16x16x32_bf16(aH[kk], bB[kk*2+1], acc[1], 0, 0, 0);
      }
    }
    #pragma unroll
    for (int n = 0; n < 2; ++n)
      #pragma unroll
      for (int q = 0; q < 4; ++q){
        int r = lg*4 + q, c = colb + n*16 + l15;
        int g = row0 + r;
        float cj = mod[256 + c];
        float y2 = acc[n][q] + fb2[c];
        out[g*CC + c] = (x[g*CC + c] + cj*y2) * rsqrtf(1.f + cj*cj);
      }
  }
}

extern "C" void kernel_launch(void* const* d_in, const int* in_sizes, int n_in,
                              void* d_out, int out_size, void* d_ws, size_t ws_size,
                              hipStream_t stream)
{
  const float* x   = (const float*)d_in[0];
  const float* te  = (const float*)d_in[1];
  const float* ce  = (const float*)d_in[2];
  const int*   ei  = (const int*)  d_in[3];
  const float* mw1 = (const float*)d_in[4];
  const float* mb1 = (const float*)d_in[5];
  const float* mw2 = (const float*)d_in[6];
  const float* mb2 = (const float*)d_in[7];
  const float* sw0 = (const float*)d_in[8];
  const float* sb0 = (const float*)d_in[9];
  const float* sw1 = (const float*)d_in[10];
  const float* sb1 = (const float*)d_in[11];
  const float* wq  = (const float*)d_in[12];
  const float* bq  = (const float*)d_in[13];
  const float* wk  = (const float*)d_in[14];
  const float* bk  = (const float*)d_in[15];
  const float* wv  = (const float*)d_in[16];
  const float* bv  = (const float*)d_in[17];
  const float* wo  = (const float*)d_in[18];
  const float* bo  = (const float*)d_in[19];
  const float* fw1 = (const float*)d_in[20];
  const float* fb1 = (const float*)d_in[21];
  const float* fw2 = (const float*)d_in[22];
  const float* fb2 = (const float*)d_in[23];
  float* out = (float*)d_out;
  const int E = in_sizes[3] / 2;

  float* ws   = (float*)d_ws;
  float* mod  = ws;                           // 384 (pad 512)
  float* tbuf = ws + 512;                     // 256
  ushort* WB  = (ushort*)(ws + 1024);         // 212992 bf16 weights
  ushort* sw1b = WB;
  ushort* wqb  = WB + 16384;
  ushort* wkb  = WB + 32768;
  ushort* wvb  = WB + 49152;
  ushort* wob  = WB + 65536;
  ushort* fw1b = WB + 81920;
  ushort* fw2b = WB + 147456;
  ushort* Ybf = WB + 212992;
  ushort* Qb  = Ybf + TNODES*CC;
  ushort* Kb  = Qb  + TNODES*CC;
  ushort* Vb  = Kb  + TNODES*CC;
  ushort* Ab  = Vb  + TNODES*CC;
  int* cnt    = (int*)(Ab + TNODES*CC);       // TN counts
  int* adj    = cnt + TNODES;                 // TN*DEGCAP bucket adjacency

  const int nSB = (E + 1023) / 1024;

  s1_setup<<<256, 256, 0, stream>>>(sw1, wq, wk, wv, wo, fw1, fw2, WB, cnt, te, mw1, mb1, tbuf);
  s2_setup<<<nSB + 24, 256, 0, stream>>>(ei, E, nSB, cnt, adj, tbuf, mw2, mb2, mod);
  k2_ctx_y_qkv<<<TNODES/RT, 256, 0, stream>>>(x, ce, sw0, sb0, sw1b, sb1,
                                              wqb, bq, wkb, bk, wvb, bv, mod, Ybf, Qb, Kb, Vb);
  k4_attn<<<TNODES/8, 256, 0, stream>>>(Qb, Kb, Vb, cnt, adj, Ab);
  k5_final<<<TNODES/RT, 256, 0, stream>>>(x, Ybf, Ab, wob, bo, fw1b, fb1, fw2b, fb2, mod, out);
}

// Round 7
// 78.824 us; speedup vs baseline: 1.3184x; 1.0570x over previous
//
#include <hip/hip_runtime.h>
#include <math.h>

#define TNODES 8192
#define CC 128
#define RT 32        // rows per block for k2/k5 (512 threads, 8 waves)
#define DEGCAP 128   // bucket capacity per src; degrees ~Poisson(39)+1, max~70

typedef __attribute__((ext_vector_type(8))) short bf8;
typedef __attribute__((ext_vector_type(4))) float fx4;

__device__ __forceinline__ ushort f2b(float f){
  union { float f; uint u; } a; a.f = f;
  uint u = a.u;
  uint r = (u + 0x7fffu + ((u >> 16) & 1u)) >> 16;   // RNE
  return (ushort)r;
}
__device__ __forceinline__ float b2f(ushort s){
  union { uint u; float f; } a; a.u = ((uint)s) << 16;
  return a.f;
}
__device__ __forceinline__ float2 bpair(uint u){
  union { uint u; float f; } lo, hi;
  lo.u = u << 16; hi.u = u & 0xffff0000u;
  float2 r; r.x = lo.f; r.y = hi.f; return r;
}
#define SWZ(row, col) ((col) ^ (((row) & 7) << 3))

// ---------------- S1: weight conv (208) + zero cnt (32) + mod layer1 (16 blocks) ----------------
__global__ __launch_bounds__(256) void s1_setup(
    const float* __restrict__ sw1, const float* __restrict__ wq, const float* __restrict__ wk,
    const float* __restrict__ wv, const float* __restrict__ wo, const float* __restrict__ fw1,
    const float* __restrict__ fw2, ushort* __restrict__ dst,
    int* __restrict__ cnt,
    const float* __restrict__ te, const float* __restrict__ mw1, const float* __restrict__ mb1,
    float* __restrict__ tbuf)
{
  const int b = blockIdx.x, tid = threadIdx.x;
  if (b < 208){
    int i = (b * 256 + tid) * 4;
    const float* src; int off;
    if      (i <  16384){ src = sw1; off = i; }
    else if (i <  32768){ src = wq;  off = i - 16384; }
    else if (i <  49152){ src = wk;  off = i - 32768; }
    else if (i <  65536){ src = wv;  off = i - 49152; }
    else if (i <  81920){ src = wo;  off = i - 65536; }
    else if (i < 147456){ src = fw1; off = i - 81920; }
    else                { src = fw2; off = i - 147456; }
    float4 v = *(const float4*)&src[off];
    ushort4 o; o.x = f2b(v.x); o.y = f2b(v.y); o.z = f2b(v.z); o.w = f2b(v.w);
    *(ushort4*)&dst[i] = o;
  } else if (b < 240){
    cnt[(b - 208) * 256 + tid] = 0;
  } else {
    // mod layer1: t = silu(te @ mw1^T + mb1), 16 outputs/block, 16 threads/output
    const int og = tid >> 4, th = tid & 15;
    const int o = (b - 240) * 16 + og;
    float acc = 0.f;
    #pragma unroll
    for (int u = 0; u < 4; ++u){
      float4 w  = *(const float4*)&mw1[o*256 + th*16 + u*4];
      float4 t4 = *(const float4*)&te[th*16 + u*4];
      acc += w.x*t4.x + w.y*t4.y + w.z*t4.z + w.w*t4.w;
    }
    #pragma unroll
    for (int m = 1; m < 16; m <<= 1) acc += __shfl_xor(acc, m);
    if (th == 0){
      float z = acc + mb1[o];
      tbuf[o] = z / (1.f + __expf(-z));
    }
  }
}

// ---------------- S2: bucket scatter (no count/scan) + mod layer2 ----------------
__global__ __launch_bounds__(256) void s2_setup(
    const int* __restrict__ ei, int E, int nSB, int* __restrict__ cnt, int* __restrict__ adj,
    const float* __restrict__ tbuf, const float* __restrict__ mw2, const float* __restrict__ mb2,
    float* __restrict__ mod)
{
  const int b = blockIdx.x, tid = threadIdx.x;
  if (b < nSB){
    int e0 = (b * 256 + tid) * 4;
    if (e0 + 3 < E){
      int4 p0 = *(const int4*)&ei[2*e0];
      int4 p1 = *(const int4*)&ei[2*e0 + 4];
      int s;
      s = atomicAdd(&cnt[p0.x], 1); adj[p0.x*DEGCAP + (s & (DEGCAP-1))] = p0.y;
      s = atomicAdd(&cnt[p0.z], 1); adj[p0.z*DEGCAP + (s & (DEGCAP-1))] = p0.w;
      s = atomicAdd(&cnt[p1.x], 1); adj[p1.x*DEGCAP + (s & (DEGCAP-1))] = p1.y;
      s = atomicAdd(&cnt[p1.z], 1); adj[p1.z*DEGCAP + (s & (DEGCAP-1))] = p1.w;
    } else {
      for (int e = e0; e < E; ++e){
        int sr = ei[2*e], ds = ei[2*e+1];
        int s = atomicAdd(&cnt[sr], 1);
        adj[sr*DEGCAP + (s & (DEGCAP-1))] = ds;
      }
    }
  } else {
    const int og = tid >> 4, th = tid & 15;
    const int o = (b - nSB) * 16 + og;   // < 384
    float acc = 0.f;
    #pragma unroll
    for (int u = 0; u < 4; ++u){
      float4 w  = *(const float4*)&mw2[o*256 + th*16 + u*4];
      float4 t4 = *(const float4*)&tbuf[th*16 + u*4];
      acc += w.x*t4.x + w.y*t4.y + w.z*t4.z + w.w*t4.w;
    }
    #pragma unroll
    for (int m = 1; m < 16; m <<= 1) acc += __shfl_xor(acc, m);
    if (th == 0) mod[o] = acc + mb2[o];
  }
}

// ---------------- K2: siren -> y (LN+mod) -> QKV via MFMA (RT=32, 512 thr) ----------------
__global__ __launch_bounds__(512) void k2_ctx_y_qkv(
    const float* __restrict__ x, const float* __restrict__ ce,
    const float* __restrict__ sw0, const float* __restrict__ sb0,
    const ushort* __restrict__ sw1b, const float* __restrict__ sb1,
    const ushort* __restrict__ wqb, const float* __restrict__ bq,
    const ushort* __restrict__ wkb, const float* __restrict__ bk,
    const ushort* __restrict__ wvb, const float* __restrict__ bv,
    const float* __restrict__ mod,
    ushort* __restrict__ Ybf, ushort* __restrict__ Qb, ushort* __restrict__ Kb, ushort* __restrict__ Vb)
{
  __shared__ float  ceL[RT][8];
  __shared__ ushort hxb[RT*CC];
  __shared__ float  yL[RT][132];
  __shared__ ushort yb[RT*CC];
  const int tid  = threadIdx.x;
  const int lane = tid & 63, wave = tid >> 6;
  const int l15 = lane & 15, lg = lane >> 4;
  const int hw  = wave & 3;          // head / col-group
  const int rtb = (wave >> 2) * 16;  // row-tile base
  const int row0 = blockIdx.x * RT;

  if (tid < RT*7){ int r = tid/7, i = tid - r*7; ceL[r][i] = ce[(row0+r)*7 + i]; }
  __syncthreads();

  // hctx = sin(ce @ sw0^T + sb0) -> bf16 LDS (swizzled): 32x128 vals, 8/thread
  #pragma unroll
  for (int u = 0; u < 8; ++u){
    int idx = tid + u*512;
    int r = idx >> 7, j = idx & 127;
    float a = sb0[j];
    #pragma unroll
    for (int i = 0; i < 7; ++i) a += sw0[j*7+i]*ceL[r][i];
    hxb[r*CC + SWZ(r, j)] = f2b(__sinf(a));
  }
  __syncthreads();

  const int colb = hw*32;
  // y_pre = x + hctx @ sw1^T + sb1 (prefetched fragments)
  {
    bf8 aH[4], bB[8];
    #pragma unroll
    for (int ks = 0; ks < 4; ++ks)
      aH[ks] = *(const bf8*)&hxb[(rtb+l15)*CC + SWZ(rtb+l15, ks*32 + lg*8)];
    #pragma unroll
    for (int ks = 0; ks < 4; ++ks)
      #pragma unroll
      for (int n = 0; n < 2; ++n)
        bB[ks*2+n] = *(const bf8*)&sw1b[(colb + n*16 + l15)*CC + ks*32 + lg*8];
    fx4 acc[2]; acc[0] = 0.f; acc[1] = 0.f;
    #pragma unroll
    for (int ks = 0; ks < 4; ++ks){
      acc[0] = __builtin_amdgcn_mfma_f32_16x16x32_bf16(aH[ks], bB[ks*2+0], acc[0], 0, 0, 0);
      acc[1] = __builtin_amdgcn_mfma_f32_16x16x32_bf16(aH[ks], bB[ks*2+1], acc[1], 0, 0, 0);
    }
    #pragma unroll
    for (int n = 0; n < 2; ++n)
      #pragma unroll
      for (int q = 0; q < 4; ++q){
        int r = rtb + lg*4 + q, c = colb + n*16 + l15;
        yL[r][c] = x[(row0+r)*CC + c] + acc[n][q] + sb1[c];
      }
  }
  __syncthreads();

  // LN over 128 + (1+a)*z + b -> bf16 LDS (swizzled): 32 rows x 16 lanes
  {
    int r = tid >> 4, s16 = tid & 15;
    float4 za = *(const float4*)&yL[r][s16*8];
    float4 zb = *(const float4*)&yL[r][s16*8 + 4];
    float sum = za.x+za.y+za.z+za.w + zb.x+zb.y+zb.z+zb.w;
    float ssq = za.x*za.x+za.y*za.y+za.z*za.z+za.w*za.w
              + zb.x*zb.x+zb.y*zb.y+zb.z*zb.z+zb.w*zb.w;
    #pragma unroll
    for (int m = 1; m < 16; m <<= 1){ sum += __shfl_xor(sum, m); ssq += __shfl_xor(ssq, m); }
    float mean = sum * (1.f/128.f);
    float var  = ssq * (1.f/128.f) - mean*mean;
    float inv  = rsqrtf(var + 1e-5f);
    float zv[8] = {za.x,za.y,za.z,za.w,zb.x,zb.y,zb.z,zb.w};
    bf8 pk;
    #pragma unroll
    for (int u = 0; u < 8; ++u){
      int jj = s16*8 + u;
      float z = (zv[u] - mean) * inv;
      pk[u] = (short)f2b((1.f + mod[jj]) * z + mod[128+jj]);
    }
    *(bf8*)&yb[r*CC + SWZ(r, s16*8)] = pk;
  }
  __syncthreads();

  // store Y (bf16): 32 rows x 16 chunks
  {
    int rr = tid >> 4, b8 = tid & 15;
    bf8 v = *(const bf8*)&yb[rr*CC + SWZ(rr, b8*8)];
    *(bf8*)&Ybf[(row0+rr)*CC + b8*8] = v;
  }

  // QKV: wave = (head hw, row-tile rtb); q,k get per-head LN
  bf8 af[4];
  #pragma unroll
  for (int ks = 0; ks < 4; ++ks)
    af[ks] = *(const bf8*)&yb[(rtb+l15)*CC + SWZ(rtb+l15, ks*32 + lg*8)];

  const ushort* Wb[3] = {wqb, wkb, wvb};
  const float*  Bs[3] = {bq, bk, bv};
  ushort*       Ob[3] = {Qb, Kb, Vb};
  const int cb = hw*32;
  #pragma unroll
  for (int m = 0; m < 3; ++m){
    bf8 bB[8];
    #pragma unroll
    for (int ks = 0; ks < 4; ++ks)
      #pragma unroll
      for (int n = 0; n < 2; ++n)
        bB[ks*2+n] = *(const bf8*)&Wb[m][(cb + n*16 + l15)*CC + ks*32 + lg*8];
    fx4 acc[2]; acc[0] = 0.f; acc[1] = 0.f;
    #pragma unroll
    for (int ks = 0; ks < 4; ++ks){
      acc[0] = __builtin_amdgcn_mfma_f32_16x16x32_bf16(af[ks], bB[ks*2+0], acc[0], 0, 0, 0);
      acc[1] = __builtin_amdgcn_mfma_f32_16x16x32_bf16(af[ks], bB[ks*2+1], acc[1], 0, 0, 0);
    }
    float vals[2][4];
    #pragma unroll
    for (int n = 0; n < 2; ++n)
      #pragma unroll
      for (int q = 0; q < 4; ++q)
        vals[n][q] = acc[n][q] + Bs[m][cb + n*16 + l15];
    if (m < 2){
      #pragma unroll
      for (int q = 0; q < 4; ++q){
        float s  = vals[0][q] + vals[1][q];
        float ss = vals[0][q]*vals[0][q] + vals[1][q]*vals[1][q];
        #pragma unroll
        for (int mm = 1; mm < 16; mm <<= 1){ s += __shfl_xor(s, mm); ss += __shfl_xor(ss, mm); }
        float mean = s * (1.f/32.f);
        float var  = ss * (1.f/32.f) - mean*mean;
        float inv  = rsqrtf(var + 1e-5f);
        vals[0][q] = (vals[0][q] - mean) * inv;
        vals[1][q] = (vals[1][q] - mean) * inv;
      }
    }
    #pragma unroll
    for (int n = 0; n < 2; ++n)
      #pragma unroll
      for (int q = 0; q < 4; ++q){
        int r = rtb + lg*4 + q, c = cb + n*16 + l15;
        Ob[m][(row0+r)*CC + c] = f2b(vals[n][q]);
      }
  }
}

// ---------------- K4: edge attention, 4 srcs per wave (16 lanes each) ----------------
__global__ __launch_bounds__(256) void k4_attn(
    const ushort* __restrict__ Qb, const ushort* __restrict__ Kb, const ushort* __restrict__ Vb,
    const int* __restrict__ cnt, const int* __restrict__ adj, ushort* __restrict__ Ab)
{
  const int wave = threadIdx.x >> 6, lane = threadIdx.x & 63;
  const int quarter = lane >> 4, ql = lane & 15;   // lane owns bf16 dims 8*ql..8*ql+7
  const int src = blockIdx.x*16 + wave*4 + quarter;

  uint4 qr = *(const uint4*)&Qb[src*CC + 8*ql];
  float2 qa = bpair(qr.x), qb = bpair(qr.y), qc = bpair(qr.z), qd = bpair(qr.w);
  const float sc = 0.17677669529663687f;           // 1/sqrt(32)
  qa.x*=sc; qa.y*=sc; qb.x*=sc; qb.y*=sc; qc.x*=sc; qc.y*=sc; qd.x*=sc; qd.y*=sc;

  float a0=0.f,a1=0.f,a2=0.f,a3=0.f,a4=0.f,a5=0.f,a6=0.f,a7=0.f, dh=0.f;
  const int deg = min(cnt[src], DEGCAP);
  const int* ab = adj + src*DEGCAP;
  int dmax = deg;
  dmax = max(dmax, __shfl_xor(dmax, 16));
  dmax = max(dmax, __shfl_xor(dmax, 32));

  for (int e = 0; e < dmax; e += 4){
    int4 dd = *(const int4*)&ab[e];
    int d0 = (e   < deg) ? dd.x : 0;
    int d1 = (e+1 < deg) ? dd.y : 0;
    int d2 = (e+2 < deg) ? dd.z : 0;
    int d3 = (e+3 < deg) ? dd.w : 0;
    uint4 k0 = *(const uint4*)&Kb[d0*CC + 8*ql];
    uint4 k1 = *(const uint4*)&Kb[d1*CC + 8*ql];
    uint4 k2 = *(const uint4*)&Kb[d2*CC + 8*ql];
    uint4 k3 = *(const uint4*)&Kb[d3*CC + 8*ql];
    uint4 v0 = *(const uint4*)&Vb[d0*CC + 8*ql];
    uint4 v1 = *(const uint4*)&Vb[d1*CC + 8*ql];
    uint4 v2 = *(const uint4*)&Vb[d2*CC + 8*ql];
    uint4 v3 = *(const uint4*)&Vb[d3*CC + 8*ql];
    float2 x0, x1, x2, x3;
    x0 = bpair(k0.x); x1 = bpair(k0.y); x2 = bpair(k0.z); x3 = bpair(k0.w);
    float p0 = qa.x*x0.x+qa.y*x0.y + qb.x*x1.x+qb.y*x1.y + qc.x*x2.x+qc.y*x2.y + qd.x*x3.x+qd.y*x3.y;
    x0 = bpair(k1.x); x1 = bpair(k1.y); x2 = bpair(k1.z); x3 = bpair(k1.w);
    float p1 = qa.x*x0.x+qa.y*x0.y + qb.x*x1.x+qb.y*x1.y + qc.x*x2.x+qc.y*x2.y + qd.x*x3.x+qd.y*x3.y;
    x0 = bpair(k2.x); x1 = bpair(k2.y); x2 = bpair(k2.z); x3 = bpair(k2.w);
    float p2 = qa.x*x0.x+qa.y*x0.y + qb.x*x1.x+qb.y*x1.y + qc.x*x2.x+qc.y*x2.y + qd.x*x3.x+qd.y*x3.y;
    x0 = bpair(k3.x); x1 = bpair(k3.y); x2 = bpair(k3.z); x3 = bpair(k3.w);
    float p3 = qa.x*x0.x+qa.y*x0.y + qb.x*x1.x+qb.y*x1.y + qc.x*x2.x+qc.y*x2.y + qd.x*x3.x+qd.y*x3.y;
    // head = 4-lane group (32 dims): reduce over lanes xor 1,2
    p0 += __shfl_xor(p0, 1); p1 += __shfl_xor(p1, 1); p2 += __shfl_xor(p2, 1); p3 += __shfl_xor(p3, 1);
    p0 += __shfl_xor(p0, 2); p1 += __shfl_xor(p1, 2); p2 += __shfl_xor(p2, 2); p3 += __shfl_xor(p3, 2);
    p0 = (e   < deg) ? __expf(p0) : 0.f;
    p1 = (e+1 < deg) ? __expf(p1) : 0.f;
    p2 = (e+2 < deg) ? __expf(p2) : 0.f;
    p3 = (e+3 < deg) ? __expf(p3) : 0.f;
    x0 = bpair(v0.x); x1 = bpair(v0.y); x2 = bpair(v0.z); x3 = bpair(v0.w);
    a0 += p0*x0.x; a1 += p0*x0.y; a2 += p0*x1.x; a3 += p0*x1.y;
    a4 += p0*x2.x; a5 += p0*x2.y; a6 += p0*x3.x; a7 += p0*x3.y;
    x0 = bpair(v1.x); x1 = bpair(v1.y); x2 = bpair(v1.z); x3 = bpair(v1.w);
    a0 += p1*x0.x; a1 += p1*x0.y; a2 += p1*x1.x; a3 += p1*x1.y;
    a4 += p1*x2.x; a5 += p1*x2.y; a6 += p1*x3.x; a7 += p1*x3.y;
    x0 = bpair(v2.x); x1 = bpair(v2.y); x2 = bpair(v2.z); x3 = bpair(v2.w);
    a0 += p2*x0.x; a1 += p2*x0.y; a2 += p2*x1.x; a3 += p2*x1.y;
    a4 += p2*x2.x; a5 += p2*x2.y; a6 += p2*x3.x; a7 += p2*x3.y;
    x0 = bpair(v3.x); x1 = bpair(v3.y); x2 = bpair(v3.z); x3 = bpair(v3.w);
    a0 += p3*x0.x; a1 += p3*x0.y; a2 += p3*x1.x; a3 += p3*x1.y;
    a4 += p3*x2.x; a5 += p3*x2.y; a6 += p3*x3.x; a7 += p3*x3.y;
    dh += p0 + p1 + p2 + p3;
  }
  float invd = 1.f / fmaxf(dh, 1e-9f);
  uint4 o;
  o.x = (uint)f2b(a0*invd) | ((uint)f2b(a1*invd) << 16);
  o.y = (uint)f2b(a2*invd) | ((uint)f2b(a3*invd) << 16);
  o.z = (uint)f2b(a4*invd) | ((uint)f2b(a5*invd) << 16);
  o.w = (uint)f2b(a6*invd) | ((uint)f2b(a7*invd) << 16);
  *(uint4*)&Ab[src*CC + 8*ql] = o;
}

// ---------------- K5: wo + residual + FFN + final mix (RT=32, 512 thr) ----------------
__global__ __launch_bounds__(512) void k5_final(
    const float* __restrict__ x, const ushort* __restrict__ Ybf, const ushort* __restrict__ Ab,
    const ushort* __restrict__ wob, const float* __restrict__ bo,
    const ushort* __restrict__ fw1b, const float* __restrict__ fb1,
    const ushort* __restrict__ fw2b, const float* __restrict__ fb2,
    const float* __restrict__ mod, float* __restrict__ out)
{
  __shared__ ushort yyb[RT*CC];
  __shared__ ushort h1b[RT*512];
  const int tid  = threadIdx.x;
  const int lane = tid & 63, w = tid >> 6;      // 8 waves
  const int l15 = lane & 15, lg = lane >> 4;
  const int row0 = blockIdx.x * RT;

  // ---- wo GEMM: wave w owns cols w*16, rows 0..31 (2 row-tiles) ----
  {
    const int cw = w*16;
    bf8 aA[2][4], bB[4];
    #pragma unroll
    for (int rt = 0; rt < 2; ++rt)
      #pragma unroll
      for (int ks = 0; ks < 4; ++ks)
        aA[rt][ks] = *(const bf8*)&Ab[(row0 + rt*16 + l15)*CC + ks*32 + lg*8];
    #pragma unroll
    for (int ks = 0; ks < 4; ++ks)
      bB[ks] = *(const bf8*)&wob[(cw + l15)*CC + ks*32 + lg*8];
    fx4 acc[2]; acc[0] = 0.f; acc[1] = 0.f;
    #pragma unroll
    for (int ks = 0; ks < 4; ++ks){
      acc[0] = __builtin_amdgcn_mfma_f32_16x16x32_bf16(aA[0][ks], bB[ks], acc[0], 0, 0, 0);
      acc[1] = __builtin_amdgcn_mfma_f32_16x16x32_bf16(aA[1][ks], bB[ks], acc[1], 0, 0, 0);
    }
    #pragma unroll
    for (int rt = 0; rt < 2; ++rt)
      #pragma unroll
      for (int q = 0; q < 4; ++q){
        int r = rt*16 + lg*4 + q, c = cw + l15;
        float yy = b2f(Ybf[(row0+r)*CC + c]) + acc[rt][q] + bo[c];
        yyb[r*CC + SWZ(r, c)] = f2b(yy);
      }
  }
  __syncthreads();

  // ---- fw1 + silu: wave w owns cols w*64..w*64+63, rows 0..31 ----
  {
    const int cb1 = w*64;
    bf8 aY[2][4];
    #pragma unroll
    for (int rt = 0; rt < 2; ++rt)
      #pragma unroll
      for (int ks = 0; ks < 4; ++ks)
        aY[rt][ks] = *(const bf8*)&yyb[(rt*16+l15)*CC + SWZ(rt*16+l15, ks*32 + lg*8)];
    fx4 h[2][4];
    #pragma unroll
    for (int rt = 0; rt < 2; ++rt)
      #pragma unroll
      for (int n = 0; n < 4; ++n) h[rt][n] = 0.f;
    #pragma unroll
    for (int kp = 0; kp < 2; ++kp){
      bf8 bB[8];
      #pragma unroll
      for (int kk = 0; kk < 2; ++kk)
        #pragma unroll
        for (int n = 0; n < 4; ++n)
          bB[kk*4+n] = *(const bf8*)&fw1b[(cb1 + n*16 + l15)*CC + (kp*2+kk)*32 + lg*8];
      #pragma unroll
      for (int kk = 0; kk < 2; ++kk)
        #pragma unroll
        for (int n = 0; n < 4; ++n){
          h[0][n] = __builtin_amdgcn_mfma_f32_16x16x32_bf16(aY[0][kp*2+kk], bB[kk*4+n], h[0][n], 0, 0, 0);
          h[1][n] = __builtin_amdgcn_mfma_f32_16x16x32_bf16(aY[1][kp*2+kk], bB[kk*4+n], h[1][n], 0, 0, 0);
        }
    }
    #pragma unroll
    for (int rt = 0; rt < 2; ++rt)
      #pragma unroll
      for (int n = 0; n < 4; ++n)
        #pragma unroll
        for (int q = 0; q < 4; ++q){
          int r = rt*16 + lg*4 + q, c = cb1 + n*16 + l15;
          float z = h[rt][n][q] + fb1[c];
          float sl = z / (1.f + __expf(-z));
          h1b[r*512 + SWZ(r, c)] = f2b(sl);
        }
  }
  __syncthreads();

  // ---- fw2: wave w owns cols w*16, K=512 ----
  {
    const int cw = w*16;
    fx4 acc[2]; acc[0] = 0.f; acc[1] = 0.f;
    #pragma unroll
    for (int g4 = 0; g4 < 4; ++g4){
      bf8 aH[2][4], bB[4];
      #pragma unroll
      for (int rt = 0; rt < 2; ++rt)
        #pragma unroll
        for (int kk = 0; kk < 4; ++kk)
          aH[rt][kk] = *(const bf8*)&h1b[(rt*16+l15)*512 + SWZ(rt*16+l15, (g4*4+kk)*32 + lg*8)];
      #pragma unroll
      for (int kk = 0; kk < 4; ++kk)
        bB[kk] = *(const bf8*)&fw2b[(cw + l15)*512 + (g4*4+kk)*32 + lg*8];
      #pragma unroll
      for (int kk = 0; kk < 4; ++kk){
        acc[0] = __builtin_amdgcn_mfma_f32_16x16x32_bf16(aH[0][kk], bB[kk], acc[0], 0, 0, 0);
        acc[1] = __builtin_amdgcn_mfma_f32_16x16x32_bf16(aH[1][kk], bB[kk], acc[1], 0, 0, 0);
      }
    }
    #pragma unroll
    for (int rt = 0; rt < 2; ++rt)
      #pragma unroll
      for (int q = 0; q < 4; ++q){
        int r = rt*16 + lg*4 + q, c = cw + l15;
        int g = row0 + r;
        float cj = mod[256 + c];
        float y2 = acc[rt][q] + fb2[c];
        out[g*CC + c] = (x[g*CC + c] + cj*y2) * rsqrtf(1.f + cj*cj);
      }
  }
}

extern "C" void kernel_launch(void* const* d_in, const int* in_sizes, int n_in,
                              void* d_out, int out_size, void* d_ws, size_t ws_size,
                              hipStream_t stream)
{
  const float* x   = (const float*)d_in[0];
  const float* te  = (const float*)d_in[1];
  const float* ce  = (const float*)d_in[2];
  const int*   ei  = (const int*)  d_in[3];
  const float* mw1 = (const float*)d_in[4];
  const float* mb1 = (const float*)d_in[5];
  const float* mw2 = (const float*)d_in[6];
  const float* mb2 = (const float*)d_in[7];
  const float* sw0 = (const float*)d_in[8];
  const float* sb0 = (const float*)d_in[9];
  const float* sw1 = (const float*)d_in[10];
  const float* sb1 = (const float*)d_in[11];
  const float* wq  = (const float*)d_in[12];
  const float* bq  = (const float*)d_in[13];
  const float* wk  = (const float*)d_in[14];
  const float* bk  = (const float*)d_in[15];
  const float* wv  = (const float*)d_in[16];
  const float* bv  = (const float*)d_in[17];
  const float* wo  = (const float*)d_in[18];
  const float* bo  = (const float*)d_in[19];
  const float* fw1 = (const float*)d_in[20];
  const float* fb1 = (const float*)d_in[21];
  const float* fw2 = (const float*)d_in[22];
  const float* fb2 = (const float*)d_in[23];
  float* out = (float*)d_out;
  const int E = in_sizes[3] / 2;

  float* ws   = (float*)d_ws;
  float* mod  = ws;                           // 384 (pad 512)
  float* tbuf = ws + 512;                     // 256
  ushort* WB  = (ushort*)(ws + 1024);         // 212992 bf16 weights
  ushort* sw1b = WB;
  ushort* wqb  = WB + 16384;
  ushort* wkb  = WB + 32768;
  ushort* wvb  = WB + 49152;
  ushort* wob  = WB + 65536;
  ushort* fw1b = WB + 81920;
  ushort* fw2b = WB + 147456;
  ushort* Ybf = WB + 212992;
  ushort* Qb  = Ybf + TNODES*CC;
  ushort* Kb  = Qb  + TNODES*CC;
  ushort* Vb  = Kb  + TNODES*CC;
  ushort* Ab  = Vb  + TNODES*CC;
  int* cnt    = (int*)(Ab + TNODES*CC);       // TN counts
  int* adj    = cnt + TNODES;                 // TN*DEGCAP bucket adjacency

  const int nSB = (E + 1023) / 1024;

  s1_setup<<<256, 256, 0, stream>>>(sw1, wq, wk, wv, wo, fw1, fw2, WB, cnt, te, mw1, mb1, tbuf);
  s2_setup<<<nSB + 24, 256, 0, stream>>>(ei, E, nSB, cnt, adj, tbuf, mw2, mb2, mod);
  k2_ctx_y_qkv<<<TNODES/RT, 512, 0, stream>>>(x, ce, sw0, sb0, sw1b, sb1,
                                              wqb, bq, wkb, bk, wvb, bv, mod, Ybf, Qb, Kb, Vb);
  k4_attn<<<TNODES/16, 256, 0, stream>>>(Qb, Kb, Vb, cnt, adj, Ab);
  k5_final<<<TNODES/RT, 512, 0, stream>>>(x, Ybf, Ab, wob, bo, fw1b, fb1, fw2b, fb2, mod, out);
}

// Round 8
// 73.421 us; speedup vs baseline: 1.4154x; 1.0736x over previous
//
#include <hip/hip_runtime.h>
#include <math.h>

#define TNODES 8192
#define CC 128
#define RT 32        // rows per block for k2/k45 (512 threads, 8 waves)
#define DEGCAP 128   // bucket capacity per src; degrees ~Poisson(39)+1, max~70

typedef __attribute__((ext_vector_type(8))) short bf8;
typedef __attribute__((ext_vector_type(4))) float fx4;

__device__ __forceinline__ ushort f2b(float f){
  union { float f; uint u; } a; a.f = f;
  uint u = a.u;
  uint r = (u + 0x7fffu + ((u >> 16) & 1u)) >> 16;   // RNE
  return (ushort)r;
}
__device__ __forceinline__ float b2f(ushort s){
  union { uint u; float f; } a; a.u = ((uint)s) << 16;
  return a.f;
}
__device__ __forceinline__ float2 bpair(uint u){
  union { uint u; float f; } lo, hi;
  lo.u = u << 16; hi.u = u & 0xffff0000u;
  float2 r; r.x = lo.f; r.y = hi.f; return r;
}
#define SWZ(row, col) ((col) ^ (((row) & 7) << 3))

// ---------------- S1: weight conv (208) + zero cnt (32) + mod layer1 (16 blocks) ----------------
__global__ __launch_bounds__(256) void s1_setup(
    const float* __restrict__ sw1, const float* __restrict__ wq, const float* __restrict__ wk,
    const float* __restrict__ wv, const float* __restrict__ wo, const float* __restrict__ fw1,
    const float* __restrict__ fw2, ushort* __restrict__ dst,
    int* __restrict__ cnt,
    const float* __restrict__ te, const float* __restrict__ mw1, const float* __restrict__ mb1,
    float* __restrict__ tbuf)
{
  const int b = blockIdx.x, tid = threadIdx.x;
  if (b < 208){
    int i = (b * 256 + tid) * 4;
    const float* src; int off;
    if      (i <  16384){ src = sw1; off = i; }
    else if (i <  32768){ src = wq;  off = i - 16384; }
    else if (i <  49152){ src = wk;  off = i - 32768; }
    else if (i <  65536){ src = wv;  off = i - 49152; }
    else if (i <  81920){ src = wo;  off = i - 65536; }
    else if (i < 147456){ src = fw1; off = i - 81920; }
    else                { src = fw2; off = i - 147456; }
    float4 v = *(const float4*)&src[off];
    ushort4 o; o.x = f2b(v.x); o.y = f2b(v.y); o.z = f2b(v.z); o.w = f2b(v.w);
    *(ushort4*)&dst[i] = o;
  } else if (b < 240){
    cnt[(b - 208) * 256 + tid] = 0;
  } else {
    // mod layer1: t = silu(te @ mw1^T + mb1), 16 outputs/block, 16 threads/output
    const int og = tid >> 4, th = tid & 15;
    const int o = (b - 240) * 16 + og;
    float acc = 0.f;
    #pragma unroll
    for (int u = 0; u < 4; ++u){
      float4 w  = *(const float4*)&mw1[o*256 + th*16 + u*4];
      float4 t4 = *(const float4*)&te[th*16 + u*4];
      acc += w.x*t4.x + w.y*t4.y + w.z*t4.z + w.w*t4.w;
    }
    #pragma unroll
    for (int m = 1; m < 16; m <<= 1) acc += __shfl_xor(acc, m);
    if (th == 0){
      float z = acc + mb1[o];
      tbuf[o] = z / (1.f + __expf(-z));
    }
  }
}

// ---------------- K2: siren -> y (LN+mod) -> QKV via MFMA + modL2(a,b) + scatter blocks ----------------
__global__ __launch_bounds__(512) void k2_ctx_y_qkv(
    const float* __restrict__ x, const float* __restrict__ ce,
    const float* __restrict__ sw0, const float* __restrict__ sb0,
    const ushort* __restrict__ sw1b, const float* __restrict__ sb1,
    const ushort* __restrict__ wqb, const float* __restrict__ bq,
    const ushort* __restrict__ wkb, const float* __restrict__ bk,
    const ushort* __restrict__ wvb, const float* __restrict__ bv,
    const float* __restrict__ tbuf, const float* __restrict__ mw2, const float* __restrict__ mb2,
    ushort* __restrict__ Ybf, ushort* __restrict__ Qb, ushort* __restrict__ Kb, ushort* __restrict__ Vb,
    const int* __restrict__ ei, int E, int* __restrict__ cnt, int* __restrict__ adj)
{
  __shared__ float  ceL[RT][8];
  __shared__ float  tbL[256];
  __shared__ float  modL[256];
  __shared__ ushort hxb[RT*CC];
  __shared__ float  yL[RT][132];
  __shared__ ushort yb[RT*CC];
  const int tid  = threadIdx.x;

  if (blockIdx.x >= TNODES/RT){
    // ---- bucket scatter: 2 edges/thread ----
    const int b = blockIdx.x - TNODES/RT;
    int e0 = (b * 512 + tid) * 2;
    if (e0 + 1 < E){
      int4 p = *(const int4*)&ei[2*e0];
      int s;
      s = atomicAdd(&cnt[p.x], 1); adj[p.x*DEGCAP + (s & (DEGCAP-1))] = p.y;
      s = atomicAdd(&cnt[p.z], 1); adj[p.z*DEGCAP + (s & (DEGCAP-1))] = p.w;
    } else if (e0 < E){
      int sr = ei[2*e0], ds = ei[2*e0+1];
      int s = atomicAdd(&cnt[sr], 1);
      adj[sr*DEGCAP + (s & (DEGCAP-1))] = ds;
    }
    return;
  }

  const int lane = tid & 63, wave = tid >> 6;
  const int l15 = lane & 15, lg = lane >> 4;
  const int hw  = wave & 3;          // head / col-group
  const int rtb = (wave >> 2) * 16;  // row-tile base
  const int row0 = blockIdx.x * RT;

  if (tid < RT*7){ int r = tid/7, i = tid - r*7; ceL[r][i] = ce[(row0+r)*7 + i]; }
  if (tid < 256) tbL[tid] = tbuf[tid];
  __syncthreads();

  // hctx = sin(ce @ sw0^T + sb0) -> bf16 LDS (swizzled): 32x128 vals, 8/thread
  #pragma unroll
  for (int u = 0; u < 8; ++u){
    int idx = tid + u*512;
    int r = idx >> 7, j = idx & 127;
    float a = sb0[j];
    #pragma unroll
    for (int i = 0; i < 7; ++i) a += sw0[j*7+i]*ceL[r][i];
    hxb[r*CC + SWZ(r, j)] = f2b(__sinf(a));
  }

  // modL2 (a,b only): 256 outputs, 32 groups x 8 outputs, 16 lanes each
  {
    const int g = tid >> 4, th = tid & 15;
    #pragma unroll
    for (int it = 0; it < 8; ++it){
      int o = g*8 + it;
      float acc = 0.f;
      #pragma unroll
      for (int u = 0; u < 4; ++u){
        float4 wv = *(const float4*)&mw2[o*256 + th*16 + u*4];
        float4 t4 = *(const float4*)&tbL[th*16 + u*4];
        acc += wv.x*t4.x + wv.y*t4.y + wv.z*t4.z + wv.w*t4.w;
      }
      #pragma unroll
      for (int m = 1; m < 16; m <<= 1) acc += __shfl_xor(acc, m);
      if (th == 0) modL[o] = acc + mb2[o];
    }
  }
  __syncthreads();

  const int colb = hw*32;
  // y_pre = x + hctx @ sw1^T + sb1 (prefetched fragments)
  {
    bf8 aH[4], bB[8];
    #pragma unroll
    for (int ks = 0; ks < 4; ++ks)
      aH[ks] = *(const bf8*)&hxb[(rtb+l15)*CC + SWZ(rtb+l15, ks*32 + lg*8)];
    #pragma unroll
    for (int ks = 0; ks < 4; ++ks)
      #pragma unroll
      for (int n = 0; n < 2; ++n)
        bB[ks*2+n] = *(const bf8*)&sw1b[(colb + n*16 + l15)*CC + ks*32 + lg*8];
    fx4 acc[2]; acc[0] = 0.f; acc[1] = 0.f;
    #pragma unroll
    for (int ks = 0; ks < 4; ++ks){
      acc[0] = __builtin_amdgcn_mfma_f32_16x16x32_bf16(aH[ks], bB[ks*2+0], acc[0], 0, 0, 0);
      acc[1] = __builtin_amdgcn_mfma_f32_16x16x32_bf16(aH[ks], bB[ks*2+1], acc[1], 0, 0, 0);
    }
    #pragma unroll
    for (int n = 0; n < 2; ++n)
      #pragma unroll
      for (int q = 0; q < 4; ++q){
        int r = rtb + lg*4 + q, c = colb + n*16 + l15;
        yL[r][c] = x[(row0+r)*CC + c] + acc[n][q] + sb1[c];
      }
  }
  __syncthreads();

  // LN over 128 + (1+a)*z + b -> bf16 LDS (swizzled): 32 rows x 16 lanes
  {
    int r = tid >> 4, s16 = tid & 15;
    float4 za = *(const float4*)&yL[r][s16*8];
    float4 zb = *(const float4*)&yL[r][s16*8 + 4];
    float sum = za.x+za.y+za.z+za.w + zb.x+zb.y+zb.z+zb.w;
    float ssq = za.x*za.x+za.y*za.y+za.z*za.z+za.w*za.w
              + zb.x*zb.x+zb.y*zb.y+zb.z*zb.z+zb.w*zb.w;
    #pragma unroll
    for (int m = 1; m < 16; m <<= 1){ sum += __shfl_xor(sum, m); ssq += __shfl_xor(ssq, m); }
    float mean = sum * (1.f/128.f);
    float var  = ssq * (1.f/128.f) - mean*mean;
    float inv  = rsqrtf(var + 1e-5f);
    float zv[8] = {za.x,za.y,za.z,za.w,zb.x,zb.y,zb.z,zb.w};
    bf8 pk;
    #pragma unroll
    for (int u = 0; u < 8; ++u){
      int jj = s16*8 + u;
      float z = (zv[u] - mean) * inv;
      pk[u] = (short)f2b((1.f + modL[jj]) * z + modL[128+jj]);
    }
    *(bf8*)&yb[r*CC + SWZ(r, s16*8)] = pk;
  }
  __syncthreads();

  // store Y (bf16): 32 rows x 16 chunks
  {
    int rr = tid >> 4, b8 = tid & 15;
    bf8 v = *(const bf8*)&yb[rr*CC + SWZ(rr, b8*8)];
    *(bf8*)&Ybf[(row0+rr)*CC + b8*8] = v;
  }

  // QKV: wave = (head hw, row-tile rtb); q,k get per-head LN
  bf8 af[4];
  #pragma unroll
  for (int ks = 0; ks < 4; ++ks)
    af[ks] = *(const bf8*)&yb[(rtb+l15)*CC + SWZ(rtb+l15, ks*32 + lg*8)];

  const ushort* Wb[3] = {wqb, wkb, wvb};
  const float*  Bs[3] = {bq, bk, bv};
  ushort*       Ob[3] = {Qb, Kb, Vb};
  const int cb = hw*32;
  #pragma unroll
  for (int m = 0; m < 3; ++m){
    bf8 bB[8];
    #pragma unroll
    for (int ks = 0; ks < 4; ++ks)
      #pragma unroll
      for (int n = 0; n < 2; ++n)
        bB[ks*2+n] = *(const bf8*)&Wb[m][(cb + n*16 + l15)*CC + ks*32 + lg*8];
    fx4 acc[2]; acc[0] = 0.f; acc[1] = 0.f;
    #pragma unroll
    for (int ks = 0; ks < 4; ++ks){
      acc[0] = __builtin_amdgcn_mfma_f32_16x16x32_bf16(af[ks], bB[ks*2+0], acc[0], 0, 0, 0);
      acc[1] = __builtin_amdgcn_mfma_f32_16x16x32_bf16(af[ks], bB[ks*2+1], acc[1], 0, 0, 0);
    }
    float vals[2][4];
    #pragma unroll
    for (int n = 0; n < 2; ++n)
      #pragma unroll
      for (int q = 0; q < 4; ++q)
        vals[n][q] = acc[n][q] + Bs[m][cb + n*16 + l15];
    if (m < 2){
      #pragma unroll
      for (int q = 0; q < 4; ++q){
        float s  = vals[0][q] + vals[1][q];
        float ss = vals[0][q]*vals[0][q] + vals[1][q]*vals[1][q];
        #pragma unroll
        for (int mm = 1; mm < 16; mm <<= 1){ s += __shfl_xor(s, mm); ss += __shfl_xor(ss, mm); }
        float mean = s * (1.f/32.f);
        float var  = ss * (1.f/32.f) - mean*mean;
        float inv  = rsqrtf(var + 1e-5f);
        vals[0][q] = (vals[0][q] - mean) * inv;
        vals[1][q] = (vals[1][q] - mean) * inv;
      }
    }
    #pragma unroll
    for (int n = 0; n < 2; ++n)
      #pragma unroll
      for (int q = 0; q < 4; ++q){
        int r = rtb + lg*4 + q, c = cb + n*16 + l15;
        Ob[m][(row0+r)*CC + c] = f2b(vals[n][q]);
      }
  }
}

// ---------------- K45: edge attention (LDS A) + wo + residual + FFN + final mix ----------------
__global__ __launch_bounds__(512) void k45_attn_ffn(
    const float* __restrict__ x, const ushort* __restrict__ Ybf,
    const ushort* __restrict__ Qb, const ushort* __restrict__ Kb, const ushort* __restrict__ Vb,
    const int* __restrict__ cnt, const int* __restrict__ adj,
    const ushort* __restrict__ wob, const float* __restrict__ bo,
    const ushort* __restrict__ fw1b, const float* __restrict__ fb1,
    const ushort* __restrict__ fw2b, const float* __restrict__ fb2,
    const float* __restrict__ tbuf, const float* __restrict__ mw2, const float* __restrict__ mb2,
    float* __restrict__ out)
{
  __shared__ float  tbL[256];
  __shared__ float  cL[128];
  __shared__ ushort aLb[RT*CC];
  __shared__ ushort yyb[RT*CC];
  __shared__ ushort h1b[RT*512];
  const int tid  = threadIdx.x;
  const int lane = tid & 63, w = tid >> 6;      // 8 waves
  const int l15 = lane & 15, lg = lane >> 4;
  const int row0 = blockIdx.x * RT;

  if (tid < 256) tbL[tid] = tbuf[tid];
  __syncthreads();

  // mod c (redundant): 128 outputs, 32 groups x 4, 16 lanes each
  {
    const int g = tid >> 4, th = tid & 15;
    #pragma unroll
    for (int it = 0; it < 4; ++it){
      int o = g*4 + it;   // 0..127
      float acc = 0.f;
      #pragma unroll
      for (int u = 0; u < 4; ++u){
        float4 wv = *(const float4*)&mw2[(256+o)*256 + th*16 + u*4];
        float4 t4 = *(const float4*)&tbL[th*16 + u*4];
        acc += wv.x*t4.x + wv.y*t4.y + wv.z*t4.z + wv.w*t4.w;
      }
      #pragma unroll
      for (int m = 1; m < 16; m <<= 1) acc += __shfl_xor(acc, m);
      if (th == 0) cL[o] = acc + mb2[256+o];
    }
  }

  // ---- attention: 8 waves x 4 srcs (16 lanes each), A -> LDS (swizzled) ----
  {
    const int quarter = lane >> 4, ql = lane & 15;   // lane owns bf16 dims 8*ql..8*ql+7
    const int src = row0 + w*4 + quarter;

    uint4 qr = *(const uint4*)&Qb[src*CC + 8*ql];
    float2 qa = bpair(qr.x), qb = bpair(qr.y), qc = bpair(qr.z), qd = bpair(qr.w);
    const float sc = 0.17677669529663687f;           // 1/sqrt(32)
    qa.x*=sc; qa.y*=sc; qb.x*=sc; qb.y*=sc; qc.x*=sc; qc.y*=sc; qd.x*=sc; qd.y*=sc;

    float a0=0.f,a1=0.f,a2=0.f,a3=0.f,a4=0.f,a5=0.f,a6=0.f,a7=0.f, dh=0.f;
    const int deg = min(cnt[src], DEGCAP);
    const int* ab = adj + src*DEGCAP;
    int dmax = deg;
    dmax = max(dmax, __shfl_xor(dmax, 16));
    dmax = max(dmax, __shfl_xor(dmax, 32));

    for (int e = 0; e < dmax; e += 4){
      int4 dd = *(const int4*)&ab[e];
      int d0 = (e   < deg) ? dd.x : 0;
      int d1 = (e+1 < deg) ? dd.y : 0;
      int d2 = (e+2 < deg) ? dd.z : 0;
      int d3 = (e+3 < deg) ? dd.w : 0;
      uint4 k0 = *(const uint4*)&Kb[d0*CC + 8*ql];
      uint4 k1 = *(const uint4*)&Kb[d1*CC + 8*ql];
      uint4 k2 = *(const uint4*)&Kb[d2*CC + 8*ql];
      uint4 k3 = *(const uint4*)&Kb[d3*CC + 8*ql];
      uint4 v0 = *(const uint4*)&Vb[d0*CC + 8*ql];
      uint4 v1 = *(const uint4*)&Vb[d1*CC + 8*ql];
      uint4 v2 = *(const uint4*)&Vb[d2*CC + 8*ql];
      uint4 v3 = *(const uint4*)&Vb[d3*CC + 8*ql];
      float2 x0, x1, x2, x3;
      x0 = bpair(k0.x); x1 = bpair(k0.y); x2 = bpair(k0.z); x3 = bpair(k0.w);
      float p0 = qa.x*x0.x+qa.y*x0.y + qb.x*x1.x+qb.y*x1.y + qc.x*x2.x+qc.y*x2.y + qd.x*x3.x+qd.y*x3.y;
      x0 = bpair(k1.x); x1 = bpair(k1.y); x2 = bpair(k1.z); x3 = bpair(k1.w);
      float p1 = qa.x*x0.x+qa.y*x0.y + qb.x*x1.x+qb.y*x1.y + qc.x*x2.x+qc.y*x2.y + qd.x*x3.x+qd.y*x3.y;
      x0 = bpair(k2.x); x1 = bpair(k2.y); x2 = bpair(k2.z); x3 = bpair(k2.w);
      float p2 = qa.x*x0.x+qa.y*x0.y + qb.x*x1.x+qb.y*x1.y + qc.x*x2.x+qc.y*x2.y + qd.x*x3.x+qd.y*x3.y;
      x0 = bpair(k3.x); x1 = bpair(k3.y); x2 = bpair(k3.z); x3 = bpair(k3.w);
      float p3 = qa.x*x0.x+qa.y*x0.y + qb.x*x1.x+qb.y*x1.y + qc.x*x2.x+qc.y*x2.y + qd.x*x3.x+qd.y*x3.y;
      p0 += __shfl_xor(p0, 1); p1 += __shfl_xor(p1, 1); p2 += __shfl_xor(p2, 1); p3 += __shfl_xor(p3, 1);
      p0 += __shfl_xor(p0, 2); p1 += __shfl_xor(p1, 2); p2 += __shfl_xor(p2, 2); p3 += __shfl_xor(p3, 2);
      p0 = (e   < deg) ? __expf(p0) : 0.f;
      p1 = (e+1 < deg) ? __expf(p1) : 0.f;
      p2 = (e+2 < deg) ? __expf(p2) : 0.f;
      p3 = (e+3 < deg) ? __expf(p3) : 0.f;
      x0 = bpair(v0.x); x1 = bpair(v0.y); x2 = bpair(v0.z); x3 = bpair(v0.w);
      a0 += p0*x0.x; a1 += p0*x0.y; a2 += p0*x1.x; a3 += p0*x1.y;
      a4 += p0*x2.x; a5 += p0*x2.y; a6 += p0*x3.x; a7 += p0*x3.y;
      x0 = bpair(v1.x); x1 = bpair(v1.y); x2 = bpair(v1.z); x3 = bpair(v1.w);
      a0 += p1*x0.x; a1 += p1*x0.y; a2 += p1*x1.x; a3 += p1*x1.y;
      a4 += p1*x2.x; a5 += p1*x2.y; a6 += p1*x3.x; a7 += p1*x3.y;
      x0 = bpair(v2.x); x1 = bpair(v2.y); x2 = bpair(v2.z); x3 = bpair(v2.w);
      a0 += p2*x0.x; a1 += p2*x0.y; a2 += p2*x1.x; a3 += p2*x1.y;
      a4 += p2*x2.x; a5 += p2*x2.y; a6 += p2*x3.x; a7 += p2*x3.y;
      x0 = bpair(v3.x); x1 = bpair(v3.y); x2 = bpair(v3.z); x3 = bpair(v3.w);
      a0 += p3*x0.x; a1 += p3*x0.y; a2 += p3*x1.x; a3 += p3*x1.y;
      a4 += p3*x2.x; a5 += p3*x2.y; a6 += p3*x3.x; a7 += p3*x3.y;
      dh += p0 + p1 + p2 + p3;
    }
    float invd = 1.f / fmaxf(dh, 1e-9f);
    uint4 o4;
    o4.x = (uint)f2b(a0*invd) | ((uint)f2b(a1*invd) << 16);
    o4.y = (uint)f2b(a2*invd) | ((uint)f2b(a3*invd) << 16);
    o4.z = (uint)f2b(a4*invd) | ((uint)f2b(a5*invd) << 16);
    o4.w = (uint)f2b(a6*invd) | ((uint)f2b(a7*invd) << 16);
    int r = w*4 + quarter;
    *(uint4*)&aLb[r*CC + SWZ(r, 8*ql)] = o4;
  }
  __syncthreads();

  // ---- wo GEMM: wave w owns cols w*16, rows 0..31 (A from LDS) ----
  {
    const int cw = w*16;
    bf8 aA[2][4], bB[4];
    #pragma unroll
    for (int rt = 0; rt < 2; ++rt)
      #pragma unroll
      for (int ks = 0; ks < 4; ++ks)
        aA[rt][ks] = *(const bf8*)&aLb[(rt*16+l15)*CC + SWZ(rt*16+l15, ks*32 + lg*8)];
    #pragma unroll
    for (int ks = 0; ks < 4; ++ks)
      bB[ks] = *(const bf8*)&wob[(cw + l15)*CC + ks*32 + lg*8];
    fx4 acc[2]; acc[0] = 0.f; acc[1] = 0.f;
    #pragma unroll
    for (int ks = 0; ks < 4; ++ks){
      acc[0] = __builtin_amdgcn_mfma_f32_16x16x32_bf16(aA[0][ks], bB[ks], acc[0], 0, 0, 0);
      acc[1] = __builtin_amdgcn_mfma_f32_16x16x32_bf16(aA[1][ks], bB[ks], acc[1], 0, 0, 0);
    }
    #pragma unroll
    for (int rt = 0; rt < 2; ++rt)
      #pragma unroll
      for (int q = 0; q < 4; ++q){
        int r = rt*16 + lg*4 + q, c = cw + l15;
        float yy = b2f(Ybf[(row0+r)*CC + c]) + acc[rt][q] + bo[c];
        yyb[r*CC + SWZ(r, c)] = f2b(yy);
      }
  }
  __syncthreads();

  // ---- fw1 + silu: wave w owns cols w*64..w*64+63, rows 0..31 ----
  {
    const int cb1 = w*64;
    bf8 aY[2][4];
    #pragma unroll
    for (int rt = 0; rt < 2; ++rt)
      #pragma unroll
      for (int ks = 0; ks < 4; ++ks)
        aY[rt][ks] = *(const bf8*)&yyb[(rt*16+l15)*CC + SWZ(rt*16+l15, ks*32 + lg*8)];
    fx4 h[2][4];
    #pragma unroll
    for (int rt = 0; rt < 2; ++rt)
      #pragma unroll
      for (int n = 0; n < 4; ++n) h[rt][n] = 0.f;
    #pragma unroll
    for (int kp = 0; kp < 2; ++kp){
      bf8 bB[8];
      #pragma unroll
      for (int kk = 0; kk < 2; ++kk)
        #pragma unroll
        for (int n = 0; n < 4; ++n)
          bB[kk*4+n] = *(const bf8*)&fw1b[(cb1 + n*16 + l15)*CC + (kp*2+kk)*32 + lg*8];
      #pragma unroll
      for (int kk = 0; kk < 2; ++kk)
        #pragma unroll
        for (int n = 0; n < 4; ++n){
          h[0][n] = __builtin_amdgcn_mfma_f32_16x16x32_bf16(aY[0][kp*2+kk], bB[kk*4+n], h[0][n], 0, 0, 0);
          h[1][n] = __builtin_amdgcn_mfma_f32_16x16x32_bf16(aY[1][kp*2+kk], bB[kk*4+n], h[1][n], 0, 0, 0);
        }
    }
    #pragma unroll
    for (int rt = 0; rt < 2; ++rt)
      #pragma unroll
      for (int n = 0; n < 4; ++n)
        #pragma unroll
        for (int q = 0; q < 4; ++q){
          int r = rt*16 + lg*4 + q, c = cb1 + n*16 + l15;
          float z = h[rt][n][q] + fb1[c];
          float sl = z / (1.f + __expf(-z));
          h1b[r*512 + SWZ(r, c)] = f2b(sl);
        }
  }
  __syncthreads();

  // ---- fw2: wave w owns cols w*16, K=512 ----
  {
    const int cw = w*16;
    fx4 acc[2]; acc[0] = 0.f; acc[1] = 0.f;
    #pragma unroll
    for (int g4 = 0; g4 < 4; ++g4){
      bf8 aH[2][4], bB[4];
      #pragma unroll
      for (int rt = 0; rt < 2; ++rt)
        #pragma unroll
        for (int kk = 0; kk < 4; ++kk)
          aH[rt][kk] = *(const bf8*)&h1b[(rt*16+l15)*512 + SWZ(rt*16+l15, (g4*4+kk)*32 + lg*8)];
      #pragma unroll
      for (int kk = 0; kk < 4; ++kk)
        bB[kk] = *(const bf8*)&fw2b[(cw + l15)*512 + (g4*4+kk)*32 + lg*8];
      #pragma unroll
      for (int kk = 0; kk < 4; ++kk){
        acc[0] = __builtin_amdgcn_mfma_f32_16x16x32_bf16(aH[0][kk], bB[kk], acc[0], 0, 0, 0);
        acc[1] = __builtin_amdgcn_mfma_f32_16x16x32_bf16(aH[1][kk], bB[kk], acc[1], 0, 0, 0);
      }
    }
    #pragma unroll
    for (int rt = 0; rt < 2; ++rt)
      #pragma unroll
      for (int q = 0; q < 4; ++q){
        int r = rt*16 + lg*4 + q, c = cw + l15;
        int g = row0 + r;
        float cj = cL[c];
        float y2 = acc[rt][q] + fb2[c];
        out[g*CC + c] = (x[g*CC + c] + cj*y2) * rsqrtf(1.f + cj*cj);
      }
  }
}

extern "C" void kernel_launch(void* const* d_in, const int* in_sizes, int n_in,
                              void* d_out, int out_size, void* d_ws, size_t ws_size,
                              hipStream_t stream)
{
  const float* x   = (const float*)d_in[0];
  const float* te  = (const float*)d_in[1];
  const float* ce  = (const float*)d_in[2];
  const int*   ei  = (const int*)  d_in[3];
  const float* mw1 = (const float*)d_in[4];
  const float* mb1 = (const float*)d_in[5];
  const float* mw2 = (const float*)d_in[6];
  const float* mb2 = (const float*)d_in[7];
  const float* sw0 = (const float*)d_in[8];
  const float* sb0 = (const float*)d_in[9];
  const float* sw1 = (const float*)d_in[10];
  const float* sb1 = (const float*)d_in[11];
  const float* wq  = (const float*)d_in[12];
  const float* bq  = (const float*)d_in[13];
  const float* wk  = (const float*)d_in[14];
  const float* bk  = (const float*)d_in[15];
  const float* wv  = (const float*)d_in[16];
  const float* bv  = (const float*)d_in[17];
  const float* wo  = (const float*)d_in[18];
  const float* bo  = (const float*)d_in[19];
  const float* fw1 = (const float*)d_in[20];
  const float* fb1 = (const float*)d_in[21];
  const float* fw2 = (const float*)d_in[22];
  const float* fb2 = (const float*)d_in[23];
  float* out = (float*)d_out;
  const int E = in_sizes[3] / 2;

  float* ws   = (float*)d_ws;
  float* tbuf = ws;                           // 256 (pad 1024)
  ushort* WB  = (ushort*)(ws + 1024);         // 212992 bf16 weights
  ushort* sw1b = WB;
  ushort* wqb  = WB + 16384;
  ushort* wkb  = WB + 32768;
  ushort* wvb  = WB + 49152;
  ushort* wob  = WB + 65536;
  ushort* fw1b = WB + 81920;
  ushort* fw2b = WB + 147456;
  ushort* Ybf = WB + 212992;
  ushort* Qb  = Ybf + TNODES*CC;
  ushort* Kb  = Qb  + TNODES*CC;
  ushort* Vb  = Kb  + TNODES*CC;
  int* cnt    = (int*)(Vb + TNODES*CC);       // TN counts
  int* adj    = cnt + TNODES;                 // TN*DEGCAP bucket adjacency

  const int nSB = (E + 1023) / 1024;

  s1_setup<<<256, 256, 0, stream>>>(sw1, wq, wk, wv, wo, fw1, fw2, WB, cnt, te, mw1, mb1, tbuf);
  k2_ctx_y_qkv<<<TNODES/RT + nSB, 512, 0, stream>>>(x, ce, sw0, sb0, sw1b, sb1,
                                              wqb, bq, wkb, bk, wvb, bv,
                                              tbuf, mw2, mb2, Ybf, Qb, Kb, Vb,
                                              ei, E, cnt, adj);
  k45_attn_ffn<<<TNODES/RT, 512, 0, stream>>>(x, Ybf, Qb, Kb, Vb, cnt, adj,
                                              wob, bo, fw1b, fb1, fw2b, fb2,
                                              tbuf, mw2, mb2, out);
}